// Round 9
// baseline (339.842 us; speedup 1.0000x reference)
//
#include <hip/hip_runtime.h>
#include <hip/hip_bf16.h>
#include <math.h>

// ViT block, B=32 S=256 D=768 H=12 HD=64 MLP=3072. fp32 I/O, bf16 MFMA inside.
//
// ws layout (total ~97.9 MB):
//   [0,        25165824)  out1 fp32 [8192][768] residual trunk; hb bf16 pre-attn
//   [25165824, 37748736)  q bf16 ; h2 bf16 after attn ; fc2 bf16 partial p0 after fc1
//   [37748736, 50331648)  k  bf16             ; overlaid by mb after attn
//   [50331648, 62914560)  vt bf16 [B,H,64,S]  ; overlaid by mb after attn
//   [37748736, 88080384)  mb bf16 [8192][3072] gelu(fc1)
//   [88080384, 88375296)  Wc  bf16 [12][192][64] packed qkv weights
//   [88375296, 93093888)  W1b bf16 [3072][768]
//   [93093888, 97812480)  W2b bf16 [768][3072]
//   [97812480, 97821696)  bcb fp32 [12][192] packed qkv bias
// fc2 fp32 partial p1 lives in d_out (fully overwritten every call).

static constexpr int Bn = 32, Sn = 256, Dn = 768, Hn = 12, HDn = 64, MLPn = 3072;
static constexpr int NT = Bn * Sn; // 8192 tokens

typedef unsigned short ushort_t;
typedef unsigned int u32;
typedef __attribute__((ext_vector_type(8))) short short8; // 8 bf16 MFMA A/B frag
typedef __attribute__((ext_vector_type(4))) float f32x4;  // MFMA C/D frag

__device__ __forceinline__ float bf2f(ushort_t u) { return __uint_as_float(((u32)u) << 16); }
__device__ __forceinline__ float bflo(u32 w) { return __uint_as_float(w << 16); }
__device__ __forceinline__ float bfhi(u32 w) { return __uint_as_float(w & 0xffff0000u); }
__device__ __forceinline__ ushort_t f2bf(float f) { // round-to-nearest-even
  u32 u = __float_as_uint(f);
  u += 0x7fffu + ((u >> 16) & 1u);
  return (ushort_t)(u >> 16);
}

// async global->LDS 16B per lane; LDS dest = wave-uniform base + lane*16 (m97/m104)
__device__ __forceinline__ void async_cp16(const ushort_t* g, ushort_t* l) {
  __builtin_amdgcn_global_load_lds(
      (const __attribute__((address_space(1))) u32*)g,
      (__attribute__((address_space(3))) u32*)l, 16, 0, 0);
}

// ---------------- fp32 -> bf16 bulk conversion ---------------------------------
__global__ __launch_bounds__(256) void k_f2bf(const float* __restrict__ src,
                                              ushort_t* __restrict__ dst, int n4) {
  int i = blockIdx.x * 256 + threadIdx.x;
  if (i < n4) {
    float4 v = ((const float4*)src)[i];
    ushort4 o;
    o.x = f2bf(v.x); o.y = f2bf(v.y); o.z = f2bf(v.z); o.w = f2bf(v.w);
    ((ushort4*)dst)[i] = o;
  }
}

// ---------------- pack qkv weights [12][3*64][64] bf16 + bias [12][192] fp32 ----
__global__ __launch_bounds__(256) void k_pack_qkv(
    const float* __restrict__ Wq, const float* __restrict__ Wk,
    const float* __restrict__ Wv, const float* __restrict__ bq,
    const float* __restrict__ bk, const float* __restrict__ bv,
    ushort_t* __restrict__ Wc, float* __restrict__ bc)
{
  int i = blockIdx.x * 256 + threadIdx.x; // 0 .. 147455
  int h = i / 12288, rem = i - h * 12288;
  int mat = rem / 4096, w = rem - mat * 4096;
  const float* src = (mat == 0) ? Wq : ((mat == 1) ? Wk : Wv);
  Wc[i] = f2bf(src[h * 4096 + w]);
  if (i < Hn * 192) {
    int h2 = i / 192, r2 = i - h2 * 192;
    int m2 = r2 / 64, e2 = r2 - m2 * 64;
    const float* bs = (m2 == 0) ? bq : ((m2 == 1) ? bk : bv);
    bc[i] = bs[h2 * 64 + e2];
  }
}

// ---------------- kernel 1: LN1 -> bf16 (one WG per token) ---------------------
__global__ __launch_bounds__(256) void k_ln1(
    const float* __restrict__ x, const float* __restrict__ g1,
    const float* __restrict__ be1, ushort_t* __restrict__ hb)
{
  const int t = blockIdx.x, tid = threadIdx.x;
  __shared__ float red[8];
  float xv[3];
#pragma unroll
  for (int i = 0; i < 3; i++) xv[i] = x[(size_t)t * Dn + tid + i * 256];
  float s = xv[0] + xv[1] + xv[2];
#pragma unroll
  for (int off = 32; off > 0; off >>= 1) s += __shfl_down(s, off, 64);
  if ((tid & 63) == 0) red[tid >> 6] = s;
  __syncthreads();
  float mean = (red[0] + red[1] + red[2] + red[3]) * (1.0f / 768.0f);
  float d0 = xv[0] - mean, d1 = xv[1] - mean, d2 = xv[2] - mean;
  float s2 = d0 * d0 + d1 * d1 + d2 * d2;
#pragma unroll
  for (int off = 32; off > 0; off >>= 1) s2 += __shfl_down(s2, off, 64);
  if ((tid & 63) == 0) red[4 + (tid >> 6)] = s2;
  __syncthreads();
  float rstd = rsqrtf((red[4] + red[5] + red[6] + red[7]) * (1.0f / 768.0f) + 1e-5f);
#pragma unroll
  for (int i = 0; i < 3; i++) {
    int d = tid + i * 256;
    hb[(size_t)t * Dn + d] = f2bf((xv[i] - mean) * rstd * g1[d] + be1[d]);
  }
}

// ---------------- kernel 2: QKV projection via MFMA ----------------------------
__global__ __launch_bounds__(256) void k_qkv(
    const ushort_t* __restrict__ hb,  // [NT][768] bf16
    const ushort_t* __restrict__ Wc,  // [12][192][64] bf16
    const float* __restrict__ bc,     // [12][192] fp32
    ushort_t* __restrict__ qo, ushort_t* __restrict__ ko, ushort_t* __restrict__ vt)
{
  __shared__ __align__(16) ushort_t As[128 * 72];
  __shared__ __align__(16) ushort_t Ws[192 * 72];
  const int blk = blockIdx.x;         // (b*12 + h)*2 + half
  const int half = blk & 1;
  const int bh = blk >> 1;
  const int b_ = bh / Hn, h_ = bh - b_ * Hn;
  const int tid = threadIdx.x;
  const int t0 = b_ * Sn + half * 128;

  { // stage A: 128 rows x 64 cols (head slice of hb)
    int row = tid >> 1, seg = (tid & 1) * 32;
    const uint4* g = (const uint4*)(hb + (size_t)(t0 + row) * Dn + h_ * 64 + seg);
    uint4* s = (uint4*)(As + row * 72 + seg);
    s[0] = g[0]; s[1] = g[1]; s[2] = g[2]; s[3] = g[3];
  }
  { // stage W: 192 rows x 64 cols, contiguous per head
    int rr = tid >> 2, seg = (tid & 3) * 16;
    const ushort_t* gw = Wc + h_ * 12288;
#pragma unroll
    for (int p = 0; p < 3; p++) {
      int R = p * 64 + rr;
      const uint4* g = (const uint4*)(gw + R * 64 + seg);
      uint4* s = (uint4*)(Ws + R * 72 + seg);
      s[0] = g[0]; s[1] = g[1];
    }
  }
  __syncthreads();

  const int wave = tid >> 6, lane = tid & 63;
  const int wm = (wave >> 1) * 64, wn = (wave & 1) * 96;
  const int lrow = lane & 15, quad = lane >> 4;

  f32x4 acc[4][6];
#pragma unroll
  for (int mi = 0; mi < 4; mi++)
#pragma unroll
    for (int ni = 0; ni < 6; ni++) acc[mi][ni] = (f32x4){0.f, 0.f, 0.f, 0.f};

#pragma unroll
  for (int kk = 0; kk < 2; kk++) {
    short8 af[4], wf[6];
#pragma unroll
    for (int mi = 0; mi < 4; mi++)
      af[mi] = *(const short8*)(As + (wm + mi * 16 + lrow) * 72 + kk * 32 + quad * 8);
#pragma unroll
    for (int ni = 0; ni < 6; ni++)
      wf[ni] = *(const short8*)(Ws + (wn + ni * 16 + lrow) * 72 + kk * 32 + quad * 8);
#pragma unroll
    for (int mi = 0; mi < 4; mi++)
#pragma unroll
      for (int ni = 0; ni < 6; ni++)
        acc[mi][ni] = __builtin_amdgcn_mfma_f32_16x16x32_bf16(af[mi], wf[ni], acc[mi][ni], 0, 0, 0);
  }

#pragma unroll
  for (int ni = 0; ni < 6; ni++) {
    int c = wn + ni * 16 + lrow;        // 0..191, mat uniform per (wave,ni)
    int mat = c >> 6, e = c & 63;
    float bb = bc[h_ * 192 + c];
    if (mat < 2) {
      ushort_t* dst = (mat == 0) ? qo : ko;
      size_t base = (((size_t)bh) * Sn + half * 128 + wm) * HDn + e;
#pragma unroll
      for (int mi = 0; mi < 4; mi++) {
#pragma unroll
        for (int r = 0; r < 4; r++) {
          int lr = mi * 16 + quad * 4 + r;
          dst[base + (size_t)lr * HDn] = f2bf(acc[mi][ni][r] + bb);
        }
      }
    } else {
      size_t rowb = ((size_t)bh * 64 + e) * Sn + half * 128 + wm + quad * 4;
#pragma unroll
      for (int mi = 0; mi < 4; mi++) {
        ushort4 pk;
        pk.x = f2bf(acc[mi][ni][0] + bb);
        pk.y = f2bf(acc[mi][ni][1] + bb);
        pk.z = f2bf(acc[mi][ni][2] + bb);
        pk.w = f2bf(acc[mi][ni][3] + bb);
        *(ushort4*)(vt + rowb + mi * 16) = pk;
      }
    }
  }
}

// ---------------- kernel 3: MFMA flash attention -------------------------------
__global__ __launch_bounds__(256) void k_attn(
    const ushort_t* __restrict__ q,   // [bh][s][64]
    const ushort_t* __restrict__ kg_, // [bh][s][64]
    const ushort_t* __restrict__ vt,  // [bh][e=64][s=256]
    const float* __restrict__ x,
    float* __restrict__ out1)
{
  __shared__ __align__(16) ushort_t Ks[64 * 72];
  __shared__ __align__(16) ushort_t Vts[64 * 264];
  __shared__ __align__(16) ushort_t Pw[4][16 * 72];
  const int blk = blockIdx.x;          // bh*4 + quarter
  const int qtr = blk & 3, bh = blk >> 2;
  const int b_ = bh / Hn, h_ = bh - b_ * Hn;
  const int tid = threadIdx.x, wave = tid >> 6, lane = tid & 63;
  const int lr16 = lane & 15, quad = lane >> 4;
  const int s0 = qtr * 64 + wave * 16;

  { // stage Vt whole head
    int r = tid >> 2, cseg = (tid & 3) * 64;
    const uint4* g = (const uint4*)(vt + ((size_t)bh * 64 + r) * Sn + cseg);
    uint4* s = (uint4*)(Vts + r * 264 + cseg);
#pragma unroll
    for (int i = 0; i < 8; i++) s[i] = g[i];
  }

  short8 qf[2];
  {
    const ushort_t* qg = q + ((size_t)bh * Sn + s0 + lr16) * HDn + quad * 8;
    qf[0] = *(const short8*)(qg);
    qf[1] = *(const short8*)(qg + 32);
  }

  f32x4 of[4];
#pragma unroll
  for (int et = 0; et < 4; et++) of[et] = (f32x4){0.f, 0.f, 0.f, 0.f};
  float mrow[4] = {-3.0e38f, -3.0e38f, -3.0e38f, -3.0e38f};
  float lsum[4] = {0.f, 0.f, 0.f, 0.f};

  const ushort_t* kgb = kg_ + (size_t)bh * Sn * HDn;

  for (int c = 0; c < 4; c++) {
    if (c) __syncthreads();
    {
      int row = tid >> 2, seg = (tid & 3) * 16;
      const uint4* g = (const uint4*)(kgb + (size_t)(c * 64 + row) * HDn + seg);
      uint4* s = (uint4*)(Ks + row * 72 + seg);
      s[0] = g[0]; s[1] = g[1];
    }
    __syncthreads();

    f32x4 sc[4];
#pragma unroll
    for (int ni = 0; ni < 4; ni++) sc[ni] = (f32x4){0.f, 0.f, 0.f, 0.f};
#pragma unroll
    for (int kk = 0; kk < 2; kk++) {
#pragma unroll
      for (int ni = 0; ni < 4; ni++) {
        short8 kf = *(const short8*)(Ks + (ni * 16 + lr16) * 72 + kk * 32 + quad * 8);
        sc[ni] = __builtin_amdgcn_mfma_f32_16x16x32_bf16(qf[kk], kf, sc[ni], 0, 0, 0);
      }
    }

    float alpha[4];
#pragma unroll
    for (int r = 0; r < 4; r++) {
      float m_ = fmaxf(fmaxf(sc[0][r], sc[1][r]), fmaxf(sc[2][r], sc[3][r]));
#pragma unroll
      for (int msk = 8; msk >= 1; msk >>= 1) m_ = fmaxf(m_, __shfl_xor(m_, msk, 64));
      float mn = fmaxf(mrow[r], m_);
      alpha[r] = __expf((mrow[r] - mn) * 0.125f);
      mrow[r] = mn;
    }
#pragma unroll
    for (int ni = 0; ni < 4; ni++) {
#pragma unroll
      for (int r = 0; r < 4; r++) {
        float p = __expf((sc[ni][r] - mrow[r]) * 0.125f);
        sc[ni][r] = p;
        Pw[wave][(quad * 4 + r) * 72 + ni * 16 + lr16] = f2bf(p);
      }
    }
#pragma unroll
    for (int r = 0; r < 4; r++) {
      float s_ = (sc[0][r] + sc[1][r]) + (sc[2][r] + sc[3][r]);
#pragma unroll
      for (int msk = 8; msk >= 1; msk >>= 1) s_ += __shfl_xor(s_, msk, 64);
      lsum[r] = lsum[r] * alpha[r] + s_;
    }
#pragma unroll
    for (int et = 0; et < 4; et++)
#pragma unroll
      for (int r = 0; r < 4; r++) of[et][r] *= alpha[r];

    short8 pf0 = *(const short8*)(&Pw[wave][lr16 * 72 + quad * 8]);
    short8 pf1 = *(const short8*)(&Pw[wave][lr16 * 72 + 32 + quad * 8]);
#pragma unroll
    for (int et = 0; et < 4; et++) {
      short8 vf0 = *(const short8*)(Vts + (et * 16 + lr16) * 264 + c * 64 + quad * 8);
      short8 vf1 = *(const short8*)(Vts + (et * 16 + lr16) * 264 + c * 64 + 32 + quad * 8);
      of[et] = __builtin_amdgcn_mfma_f32_16x16x32_bf16(pf0, vf0, of[et], 0, 0, 0);
      of[et] = __builtin_amdgcn_mfma_f32_16x16x32_bf16(pf1, vf1, of[et], 0, 0, 0);
    }
  }

  const size_t obase = ((size_t)b_ * Sn + s0) * Dn + h_ * 64;
#pragma unroll
  for (int r = 0; r < 4; r++) {
    float rl = 1.0f / lsum[r];
    int row = quad * 4 + r;
#pragma unroll
    for (int et = 0; et < 4; et++) {
      size_t idx = obase + (size_t)row * Dn + et * 16 + lr16;
      out1[idx] = of[et][r] * rl + x[idx];
    }
  }
}

// ---------------- kernel 4: LN2 (one WG per token) -----------------------------
__global__ __launch_bounds__(256) void k_ln2(
    const float* __restrict__ in, const float* __restrict__ g2,
    const float* __restrict__ be2, ushort_t* __restrict__ h2)
{
  const int t = blockIdx.x, tid = threadIdx.x;
  __shared__ float red[8];
  float xv[3];
#pragma unroll
  for (int i = 0; i < 3; i++) xv[i] = in[(size_t)t * Dn + tid + i * 256];
  float s = xv[0] + xv[1] + xv[2];
#pragma unroll
  for (int off = 32; off > 0; off >>= 1) s += __shfl_down(s, off, 64);
  if ((tid & 63) == 0) red[tid >> 6] = s;
  __syncthreads();
  float mean = (red[0] + red[1] + red[2] + red[3]) * (1.0f / 768.0f);
  float d0 = xv[0] - mean, d1 = xv[1] - mean, d2 = xv[2] - mean;
  float s2 = d0 * d0 + d1 * d1 + d2 * d2;
#pragma unroll
  for (int off = 32; off > 0; off >>= 1) s2 += __shfl_down(s2, off, 64);
  if ((tid & 63) == 0) red[4 + (tid >> 6)] = s2;
  __syncthreads();
  float rstd = rsqrtf((red[4] + red[5] + red[6] + red[7]) * (1.0f / 768.0f) + 1e-5f);
#pragma unroll
  for (int i = 0; i < 3; i++) {
    int d = tid + i * 256;
    h2[(size_t)t * Dn + d] = f2bf((xv[i] - mean) * rstd * g2[d] + be2[d]);
  }
}

// -- kernels 5/6: MFMA GEMM, BK=64 double-stage + XOR-swizzled LDS, C = A*B^T ---
// 128x128 tile. Staging swizzle: LDS slot (row,s) holds global K-seg s^key(row),
// key(row)=(row>>2)&3 -> b128 frag-read phases cover all 32 banks (2-way, free)
// instead of 8 banks (8-way). bf16 outs go through a single-pass LDS-coalesced
// epilogue (Cs 128x136 unioned over staging); fp32 partial stores direct.
template <int KDIM, bool GELU, bool PARTIAL>
__global__ __launch_bounds__(256) void k_gemm(
    const ushort_t* __restrict__ A,   // [M][KDIM] bf16
    const ushort_t* __restrict__ Bw,  // [N][KDIM] bf16
    const float* __restrict__ bias,   // [N] fp32 (GELU only)
    ushort_t* __restrict__ CoutB,     // bf16 out
    float* __restrict__ CoutF,        // fp32 out
    int N)
{
  __shared__ __align__(16) ushort_t smem[17408]; // 2x(As+Bs)=32KB staging / Cs 128x136
  ushort_t* Asb[2] = { smem, smem + 8192 };
  ushort_t* Bsb[2] = { smem + 4096, smem + 12288 };
  ushort_t* Cs = smem;
  const int tid = threadIdx.x;
  const int m0 = blockIdx.y * 128, n0 = blockIdx.x * 128;
  const int wave = tid >> 6, lane = tid & 63;
  const int wm = (wave >> 1) << 6, wn = (wave & 1) << 6;
  const int lrow = lane & 15, quad = lane >> 4;
  const int lrow4 = lane >> 2;                  // staging row within 16-row group
  const int scol8 = (((lane & 3) ^ ((lane >> 4) & 3))) * 8; // swizzled global seg
  const int rq8 = ((quad ^ ((lane >> 2) & 3))) * 8;         // swizzled read seg

  f32x4 acc[4][4];
#pragma unroll
  for (int mi = 0; mi < 4; mi++)
#pragma unroll
    for (int ni = 0; ni < 4; ni++) acc[mi][ni] = (f32x4){0.f, 0.f, 0.f, 0.f};

  const int kbeg = PARTIAL ? blockIdx.z * (KDIM / 2) : 0;
  const int kend = kbeg + (PARTIAL ? KDIM / 2 : KDIM);

  for (int k0 = kbeg; k0 < kend; k0 += 64) {
#pragma unroll
    for (int t = 0; t < 2; t++) {
#pragma unroll
      for (int a = 0; a < 2; a++) {
        int rr = wave * 16 + a * 64;
        async_cp16(A + (size_t)(m0 + rr + lrow4) * KDIM + k0 + t * 32 + scol8, Asb[t] + rr * 32);
        async_cp16(Bw + (size_t)(n0 + rr + lrow4) * KDIM + k0 + t * 32 + scol8, Bsb[t] + rr * 32);
      }
    }
    __syncthreads();
#pragma unroll
    for (int t = 0; t < 2; t++) {
      short8 af[4], bfv[4];
#pragma unroll
      for (int mi = 0; mi < 4; mi++)
        af[mi] = *(const short8*)(Asb[t] + (wm + mi * 16 + lrow) * 32 + rq8);
#pragma unroll
      for (int ni = 0; ni < 4; ni++)
        bfv[ni] = *(const short8*)(Bsb[t] + (wn + ni * 16 + lrow) * 32 + rq8);
#pragma unroll
      for (int mi = 0; mi < 4; mi++)
#pragma unroll
        for (int ni = 0; ni < 4; ni++)
          acc[mi][ni] = __builtin_amdgcn_mfma_f32_16x16x32_bf16(af[mi], bfv[ni], acc[mi][ni], 0, 0, 0);
    }
    __syncthreads();
  }

  if (GELU || blockIdx.z == 0) {
    // single-pass coalesced bf16 epilogue (staging LDS is dead after last barrier)
#pragma unroll
    for (int ni = 0; ni < 4; ni++) {
      int col = wn + ni * 16 + lrow;
      float bc = GELU ? bias[n0 + col] : 0.f;
#pragma unroll
      for (int mi = 0; mi < 4; mi++) {
#pragma unroll
        for (int r = 0; r < 4; r++) {
          float vv = acc[mi][ni][r] + bc;
          float o = GELU ? (0.5f * vv * (1.0f + erff(vv * 0.70710678f))) : vv;
          Cs[(wm + mi * 16 + quad * 4 + r) * 136 + col] = f2bf(o);
        }
      }
    }
    __syncthreads();
    int row = tid >> 1, part = tid & 1;
    const uint4* s = (const uint4*)(Cs + row * 136 + part * 64);
    uint4* d = (uint4*)(CoutB + (size_t)(m0 + row) * N + n0 + part * 64);
#pragma unroll
    for (int i = 0; i < 8; i++) d[i] = s[i];
  } else {
    // fp32 partial: 16 lanes x 4B = full 64B segments, direct stores are fine
#pragma unroll
    for (int ni = 0; ni < 4; ni++) {
      int col = n0 + wn + ni * 16 + lrow;
#pragma unroll
      for (int mi = 0; mi < 4; mi++) {
#pragma unroll
        for (int r = 0; r < 4; r++) {
          int row = m0 + wm + mi * 16 + quad * 4 + r;
          CoutF[(size_t)row * N + col] = acc[mi][ni][r];
        }
      }
    }
  }
}

// ---------------- kernel 7: split-K reduce + bias + residual -------------------
__global__ __launch_bounds__(256) void k_reduce(
    const ushort_t* __restrict__ p0,  // bf16 partial [8192][768]
    const float* __restrict__ p1,     // fp32 partial (aliases out)
    const float* __restrict__ res,    // out1
    const float* __restrict__ bias,   // bm2 [768]
    float* __restrict__ out)
{
  int i4 = blockIdx.x * 256 + threadIdx.x;     // float4 index, 1572864 total
  int col4 = (i4 % 192) * 4;
  float4 o = ((const float4*)p1)[i4];
  float4 r = ((const float4*)res)[i4];
  ushort4 a = ((const ushort4*)p0)[i4];
  o.x += bf2f(a.x) + bias[col4 + 0] + r.x;
  o.y += bf2f(a.y) + bias[col4 + 1] + r.y;
  o.z += bf2f(a.z) + bias[col4 + 2] + r.z;
  o.w += bf2f(a.w) + bias[col4 + 3] + r.w;
  ((float4*)out)[i4] = o;
}

// ---------------- launch --------------------------------------------------------
extern "C" void kernel_launch(void* const* d_in, const int* in_sizes, int n_in,
                              void* d_out, int out_size, void* d_ws, size_t ws_size,
                              hipStream_t stream) {
  (void)in_sizes; (void)n_in; (void)out_size; (void)ws_size;
  const float* x   = (const float*)d_in[0];
  const float* g1  = (const float*)d_in[1];
  const float* be1 = (const float*)d_in[2];
  const float* Wq  = (const float*)d_in[3];
  const float* bq  = (const float*)d_in[4];
  const float* Wk  = (const float*)d_in[5];
  const float* bk  = (const float*)d_in[6];
  const float* Wv  = (const float*)d_in[7];
  const float* bv  = (const float*)d_in[8];
  const float* g2  = (const float*)d_in[9];
  const float* be2 = (const float*)d_in[10];
  const float* W1  = (const float*)d_in[11];
  const float* bm1 = (const float*)d_in[12];
  const float* W2  = (const float*)d_in[13];
  const float* bm2 = (const float*)d_in[14];
  float* outp = (float*)d_out;

  char* ws = (char*)d_ws;
  float*    out1 = (float*)ws;                   // [0, 25165824)
  ushort_t* hb   = (ushort_t*)ws;                // bf16 h, pre-attn only
  ushort_t* qb   = (ushort_t*)(ws + 25165824);
  ushort_t* kb   = (ushort_t*)(ws + 37748736);
  ushort_t* vtb  = (ushort_t*)(ws + 50331648);   // V transposed [bh][64][256]
  ushort_t* h2   = qb;                           // reuse q after attn
  ushort_t* p0   = qb;                           // fc2 bf16 partial after fc1
  ushort_t* mb   = (ushort_t*)(ws + 37748736);   // overlays k,vt
  ushort_t* Wc   = (ushort_t*)(ws + 88080384);
  ushort_t* W1b  = (ushort_t*)(ws + 88375296);
  ushort_t* W2b  = (ushort_t*)(ws + 93093888);
  float*    bcb  = (float*)(ws + 97812480);

  const int nW1 = MLPn * Dn; // 2359296
  k_pack_qkv<<<dim3(576), dim3(256), 0, stream>>>(Wq, Wk, Wv, bq, bk, bv, Wc, bcb);
  k_f2bf<<<dim3(nW1 / 4 / 256), dim3(256), 0, stream>>>(W1, W1b, nW1 / 4);
  k_f2bf<<<dim3(nW1 / 4 / 256), dim3(256), 0, stream>>>(W2, W2b, nW1 / 4);

  k_ln1<<<dim3(NT), dim3(256), 0, stream>>>(x, g1, be1, hb);
  k_qkv<<<dim3(Bn * Hn * 2), dim3(256), 0, stream>>>(hb, Wc, bcb, qb, kb, vtb);
  k_attn<<<dim3(Bn * Hn * 4), dim3(256), 0, stream>>>(qb, kb, vtb, x, out1);
  k_ln2<<<dim3(NT), dim3(256), 0, stream>>>(out1, g2, be2, h2);
  // fc1: [8192][768] x [3072][768]^T -> gelu -> mb bf16
  k_gemm<Dn, true, false><<<dim3(MLPn / 128, NT / 128, 1), dim3(256), 0, stream>>>(
      h2, W1b, bm1, mb, nullptr, MLPn);
  // fc2 split-K=2: z=0 -> p0 bf16 (qb region), z=1 -> fp32 partial in d_out
  k_gemm<MLPn, false, true><<<dim3(Dn / 128, NT / 128, 2), dim3(256), 0, stream>>>(
      mb, W2b, nullptr, p0, outp, Dn);
  k_reduce<<<dim3(NT * Dn / 4 / 256), dim3(256), 0, stream>>>(p0, outp, out1, bm2, outp);
}

// Round 10
// 338.031 us; speedup vs baseline: 1.0054x; 1.0054x over previous
//
#include <hip/hip_runtime.h>
#include <hip/hip_bf16.h>
#include <math.h>

// ViT block, B=32 S=256 D=768 H=12 HD=64 MLP=3072. fp32 I/O, bf16 MFMA inside.
//
// ws layout (total ~97.9 MB):
//   [0,        25165824)  out1 fp32 [8192][768] residual trunk; hb bf16 pre-attn
//   [25165824, 37748736)  q bf16 ; h2 bf16 after attn ; fc2 bf16 partial p0 after fc1
//   [37748736, 50331648)  k  bf16             ; overlaid by mb after attn
//   [50331648, 62914560)  vt bf16 [B,H,64,S]  ; overlaid by mb after attn
//   [37748736, 88080384)  mb bf16 [8192][3072] gelu(fc1)
//   [88080384, 88375296)  Wc  bf16 [12][192][64] packed qkv weights
//   [88375296, 93093888)  W1b bf16 [3072][768]
//   [93093888, 97812480)  W2b bf16 [768][3072]
//   [97812480, 97821696)  bcb fp32 [12][192] packed qkv bias
// fc2 fp32 partial p1 lives in d_out (fully overwritten every call).
//
// Journal notes baked in:
//  - SQ_LDS_BANK_CONFLICT == 4718592 is the async-DMA LDS-write burst, NOT frag
//    read conflicts (constant across swizzle/no-swizzle, r5/r8/r9). Don't chase it.
//  - Cs epilogue must NOT be instantiated in the PARTIAL kernel (r9: VGPR 96,
//    occupancy 15.7%, FETCH 161 MB from lost L2 reuse).

static constexpr int Bn = 32, Sn = 256, Dn = 768, Hn = 12, HDn = 64, MLPn = 3072;
static constexpr int NT = Bn * Sn; // 8192 tokens

typedef unsigned short ushort_t;
typedef unsigned int u32;
typedef __attribute__((ext_vector_type(8))) short short8; // 8 bf16 MFMA A/B frag
typedef __attribute__((ext_vector_type(4))) float f32x4;  // MFMA C/D frag

__device__ __forceinline__ float bf2f(ushort_t u) { return __uint_as_float(((u32)u) << 16); }
__device__ __forceinline__ float bflo(u32 w) { return __uint_as_float(w << 16); }
__device__ __forceinline__ float bfhi(u32 w) { return __uint_as_float(w & 0xffff0000u); }
__device__ __forceinline__ ushort_t f2bf(float f) { // round-to-nearest-even
  u32 u = __float_as_uint(f);
  u += 0x7fffu + ((u >> 16) & 1u);
  return (ushort_t)(u >> 16);
}

// async global->LDS 16B per lane; LDS dest = wave-uniform base + lane*16 (m97/m104)
__device__ __forceinline__ void async_cp16(const ushort_t* g, ushort_t* l) {
  __builtin_amdgcn_global_load_lds(
      (const __attribute__((address_space(1))) u32*)g,
      (__attribute__((address_space(3))) u32*)l, 16, 0, 0);
}

// ---------------- fp32 -> bf16 bulk conversion ---------------------------------
__global__ __launch_bounds__(256) void k_f2bf(const float* __restrict__ src,
                                              ushort_t* __restrict__ dst, int n4) {
  int i = blockIdx.x * 256 + threadIdx.x;
  if (i < n4) {
    float4 v = ((const float4*)src)[i];
    ushort4 o;
    o.x = f2bf(v.x); o.y = f2bf(v.y); o.z = f2bf(v.z); o.w = f2bf(v.w);
    ((ushort4*)dst)[i] = o;
  }
}

// ---------------- pack qkv weights [12][3*64][64] bf16 + bias [12][192] fp32 ----
__global__ __launch_bounds__(256) void k_pack_qkv(
    const float* __restrict__ Wq, const float* __restrict__ Wk,
    const float* __restrict__ Wv, const float* __restrict__ bq,
    const float* __restrict__ bk, const float* __restrict__ bv,
    ushort_t* __restrict__ Wc, float* __restrict__ bc)
{
  int i = blockIdx.x * 256 + threadIdx.x; // 0 .. 147455
  int h = i / 12288, rem = i - h * 12288;
  int mat = rem / 4096, w = rem - mat * 4096;
  const float* src = (mat == 0) ? Wq : ((mat == 1) ? Wk : Wv);
  Wc[i] = f2bf(src[h * 4096 + w]);
  if (i < Hn * 192) {
    int h2 = i / 192, r2 = i - h2 * 192;
    int m2 = r2 / 64, e2 = r2 - m2 * 64;
    const float* bs = (m2 == 0) ? bq : ((m2 == 1) ? bk : bv);
    bc[i] = bs[h2 * 64 + e2];
  }
}

// ---------------- kernel 1: LN1 -> bf16 (one WG per token) ---------------------
__global__ __launch_bounds__(256) void k_ln1(
    const float* __restrict__ x, const float* __restrict__ g1,
    const float* __restrict__ be1, ushort_t* __restrict__ hb)
{
  const int t = blockIdx.x, tid = threadIdx.x;
  __shared__ float red[8];
  float xv[3];
#pragma unroll
  for (int i = 0; i < 3; i++) xv[i] = x[(size_t)t * Dn + tid + i * 256];
  float s = xv[0] + xv[1] + xv[2];
#pragma unroll
  for (int off = 32; off > 0; off >>= 1) s += __shfl_down(s, off, 64);
  if ((tid & 63) == 0) red[tid >> 6] = s;
  __syncthreads();
  float mean = (red[0] + red[1] + red[2] + red[3]) * (1.0f / 768.0f);
  float d0 = xv[0] - mean, d1 = xv[1] - mean, d2 = xv[2] - mean;
  float s2 = d0 * d0 + d1 * d1 + d2 * d2;
#pragma unroll
  for (int off = 32; off > 0; off >>= 1) s2 += __shfl_down(s2, off, 64);
  if ((tid & 63) == 0) red[4 + (tid >> 6)] = s2;
  __syncthreads();
  float rstd = rsqrtf((red[4] + red[5] + red[6] + red[7]) * (1.0f / 768.0f) + 1e-5f);
#pragma unroll
  for (int i = 0; i < 3; i++) {
    int d = tid + i * 256;
    hb[(size_t)t * Dn + d] = f2bf((xv[i] - mean) * rstd * g1[d] + be1[d]);
  }
}

// ---------------- kernel 2: QKV projection via MFMA ----------------------------
__global__ __launch_bounds__(256) void k_qkv(
    const ushort_t* __restrict__ hb,  // [NT][768] bf16
    const ushort_t* __restrict__ Wc,  // [12][192][64] bf16
    const float* __restrict__ bc,     // [12][192] fp32
    ushort_t* __restrict__ qo, ushort_t* __restrict__ ko, ushort_t* __restrict__ vt)
{
  __shared__ __align__(16) ushort_t As[128 * 72];
  __shared__ __align__(16) ushort_t Ws[192 * 72];
  const int blk = blockIdx.x;         // (b*12 + h)*2 + half
  const int half = blk & 1;
  const int bh = blk >> 1;
  const int b_ = bh / Hn, h_ = bh - b_ * Hn;
  const int tid = threadIdx.x;
  const int t0 = b_ * Sn + half * 128;

  { // stage A: 128 rows x 64 cols (head slice of hb)
    int row = tid >> 1, seg = (tid & 1) * 32;
    const uint4* g = (const uint4*)(hb + (size_t)(t0 + row) * Dn + h_ * 64 + seg);
    uint4* s = (uint4*)(As + row * 72 + seg);
    s[0] = g[0]; s[1] = g[1]; s[2] = g[2]; s[3] = g[3];
  }
  { // stage W: 192 rows x 64 cols, contiguous per head
    int rr = tid >> 2, seg = (tid & 3) * 16;
    const ushort_t* gw = Wc + h_ * 12288;
#pragma unroll
    for (int p = 0; p < 3; p++) {
      int R = p * 64 + rr;
      const uint4* g = (const uint4*)(gw + R * 64 + seg);
      uint4* s = (uint4*)(Ws + R * 72 + seg);
      s[0] = g[0]; s[1] = g[1];
    }
  }
  __syncthreads();

  const int wave = tid >> 6, lane = tid & 63;
  const int wm = (wave >> 1) * 64, wn = (wave & 1) * 96;
  const int lrow = lane & 15, quad = lane >> 4;

  f32x4 acc[4][6];
#pragma unroll
  for (int mi = 0; mi < 4; mi++)
#pragma unroll
    for (int ni = 0; ni < 6; ni++) acc[mi][ni] = (f32x4){0.f, 0.f, 0.f, 0.f};

#pragma unroll
  for (int kk = 0; kk < 2; kk++) {
    short8 af[4], wf[6];
#pragma unroll
    for (int mi = 0; mi < 4; mi++)
      af[mi] = *(const short8*)(As + (wm + mi * 16 + lrow) * 72 + kk * 32 + quad * 8);
#pragma unroll
    for (int ni = 0; ni < 6; ni++)
      wf[ni] = *(const short8*)(Ws + (wn + ni * 16 + lrow) * 72 + kk * 32 + quad * 8);
#pragma unroll
    for (int mi = 0; mi < 4; mi++)
#pragma unroll
      for (int ni = 0; ni < 6; ni++)
        acc[mi][ni] = __builtin_amdgcn_mfma_f32_16x16x32_bf16(af[mi], wf[ni], acc[mi][ni], 0, 0, 0);
  }

#pragma unroll
  for (int ni = 0; ni < 6; ni++) {
    int c = wn + ni * 16 + lrow;        // 0..191, mat uniform per (wave,ni)
    int mat = c >> 6, e = c & 63;
    float bb = bc[h_ * 192 + c];
    if (mat < 2) {
      ushort_t* dst = (mat == 0) ? qo : ko;
      size_t base = (((size_t)bh) * Sn + half * 128 + wm) * HDn + e;
#pragma unroll
      for (int mi = 0; mi < 4; mi++) {
#pragma unroll
        for (int r = 0; r < 4; r++) {
          int lr = mi * 16 + quad * 4 + r;
          dst[base + (size_t)lr * HDn] = f2bf(acc[mi][ni][r] + bb);
        }
      }
    } else {
      size_t rowb = ((size_t)bh * 64 + e) * Sn + half * 128 + wm + quad * 4;
#pragma unroll
      for (int mi = 0; mi < 4; mi++) {
        ushort4 pk;
        pk.x = f2bf(acc[mi][ni][0] + bb);
        pk.y = f2bf(acc[mi][ni][1] + bb);
        pk.z = f2bf(acc[mi][ni][2] + bb);
        pk.w = f2bf(acc[mi][ni][3] + bb);
        *(ushort4*)(vt + rowb + mi * 16) = pk;
      }
    }
  }
}

// ---------------- kernel 3: MFMA flash attention -------------------------------
__global__ __launch_bounds__(256) void k_attn(
    const ushort_t* __restrict__ q,   // [bh][s][64]
    const ushort_t* __restrict__ kg_, // [bh][s][64]
    const ushort_t* __restrict__ vt,  // [bh][e=64][s=256]
    const float* __restrict__ x,
    float* __restrict__ out1)
{
  __shared__ __align__(16) ushort_t Ks[64 * 72];
  __shared__ __align__(16) ushort_t Vts[64 * 264];
  __shared__ __align__(16) ushort_t Pw[4][16 * 72];
  const int blk = blockIdx.x;          // bh*4 + quarter
  const int qtr = blk & 3, bh = blk >> 2;
  const int b_ = bh / Hn, h_ = bh - b_ * Hn;
  const int tid = threadIdx.x, wave = tid >> 6, lane = tid & 63;
  const int lr16 = lane & 15, quad = lane >> 4;
  const int s0 = qtr * 64 + wave * 16;

  { // stage Vt whole head
    int r = tid >> 2, cseg = (tid & 3) * 64;
    const uint4* g = (const uint4*)(vt + ((size_t)bh * 64 + r) * Sn + cseg);
    uint4* s = (uint4*)(Vts + r * 264 + cseg);
#pragma unroll
    for (int i = 0; i < 8; i++) s[i] = g[i];
  }

  short8 qf[2];
  {
    const ushort_t* qg = q + ((size_t)bh * Sn + s0 + lr16) * HDn + quad * 8;
    qf[0] = *(const short8*)(qg);
    qf[1] = *(const short8*)(qg + 32);
  }

  f32x4 of[4];
#pragma unroll
  for (int et = 0; et < 4; et++) of[et] = (f32x4){0.f, 0.f, 0.f, 0.f};
  float mrow[4] = {-3.0e38f, -3.0e38f, -3.0e38f, -3.0e38f};
  float lsum[4] = {0.f, 0.f, 0.f, 0.f};

  const ushort_t* kgb = kg_ + (size_t)bh * Sn * HDn;

  for (int c = 0; c < 4; c++) {
    if (c) __syncthreads();
    {
      int row = tid >> 2, seg = (tid & 3) * 16;
      const uint4* g = (const uint4*)(kgb + (size_t)(c * 64 + row) * HDn + seg);
      uint4* s = (uint4*)(Ks + row * 72 + seg);
      s[0] = g[0]; s[1] = g[1];
    }
    __syncthreads();

    f32x4 sc[4];
#pragma unroll
    for (int ni = 0; ni < 4; ni++) sc[ni] = (f32x4){0.f, 0.f, 0.f, 0.f};
#pragma unroll
    for (int kk = 0; kk < 2; kk++) {
#pragma unroll
      for (int ni = 0; ni < 4; ni++) {
        short8 kf = *(const short8*)(Ks + (ni * 16 + lr16) * 72 + kk * 32 + quad * 8);
        sc[ni] = __builtin_amdgcn_mfma_f32_16x16x32_bf16(qf[kk], kf, sc[ni], 0, 0, 0);
      }
    }

    float alpha[4];
#pragma unroll
    for (int r = 0; r < 4; r++) {
      float m_ = fmaxf(fmaxf(sc[0][r], sc[1][r]), fmaxf(sc[2][r], sc[3][r]));
#pragma unroll
      for (int msk = 8; msk >= 1; msk >>= 1) m_ = fmaxf(m_, __shfl_xor(m_, msk, 64));
      float mn = fmaxf(mrow[r], m_);
      alpha[r] = __expf((mrow[r] - mn) * 0.125f);
      mrow[r] = mn;
    }
#pragma unroll
    for (int ni = 0; ni < 4; ni++) {
#pragma unroll
      for (int r = 0; r < 4; r++) {
        float p = __expf((sc[ni][r] - mrow[r]) * 0.125f);
        sc[ni][r] = p;
        Pw[wave][(quad * 4 + r) * 72 + ni * 16 + lr16] = f2bf(p);
      }
    }
#pragma unroll
    for (int r = 0; r < 4; r++) {
      float s_ = (sc[0][r] + sc[1][r]) + (sc[2][r] + sc[3][r]);
#pragma unroll
      for (int msk = 8; msk >= 1; msk >>= 1) s_ += __shfl_xor(s_, msk, 64);
      lsum[r] = lsum[r] * alpha[r] + s_;
    }
#pragma unroll
    for (int et = 0; et < 4; et++)
#pragma unroll
      for (int r = 0; r < 4; r++) of[et][r] *= alpha[r];

    short8 pf0 = *(const short8*)(&Pw[wave][lr16 * 72 + quad * 8]);
    short8 pf1 = *(const short8*)(&Pw[wave][lr16 * 72 + 32 + quad * 8]);
#pragma unroll
    for (int et = 0; et < 4; et++) {
      short8 vf0 = *(const short8*)(Vts + (et * 16 + lr16) * 264 + c * 64 + quad * 8);
      short8 vf1 = *(const short8*)(Vts + (et * 16 + lr16) * 264 + c * 64 + 32 + quad * 8);
      of[et] = __builtin_amdgcn_mfma_f32_16x16x32_bf16(pf0, vf0, of[et], 0, 0, 0);
      of[et] = __builtin_amdgcn_mfma_f32_16x16x32_bf16(pf1, vf1, of[et], 0, 0, 0);
    }
  }

  const size_t obase = ((size_t)b_ * Sn + s0) * Dn + h_ * 64;
#pragma unroll
  for (int r = 0; r < 4; r++) {
    float rl = 1.0f / lsum[r];
    int row = quad * 4 + r;
#pragma unroll
    for (int et = 0; et < 4; et++) {
      size_t idx = obase + (size_t)row * Dn + et * 16 + lr16;
      out1[idx] = of[et][r] * rl + x[idx];
    }
  }
}

// ---------------- kernel 4: LN2 (one WG per token) -----------------------------
__global__ __launch_bounds__(256) void k_ln2(
    const float* __restrict__ in, const float* __restrict__ g2,
    const float* __restrict__ be2, ushort_t* __restrict__ h2)
{
  const int t = blockIdx.x, tid = threadIdx.x;
  __shared__ float red[8];
  float xv[3];
#pragma unroll
  for (int i = 0; i < 3; i++) xv[i] = in[(size_t)t * Dn + tid + i * 256];
  float s = xv[0] + xv[1] + xv[2];
#pragma unroll
  for (int off = 32; off > 0; off >>= 1) s += __shfl_down(s, off, 64);
  if ((tid & 63) == 0) red[tid >> 6] = s;
  __syncthreads();
  float mean = (red[0] + red[1] + red[2] + red[3]) * (1.0f / 768.0f);
  float d0 = xv[0] - mean, d1 = xv[1] - mean, d2 = xv[2] - mean;
  float s2 = d0 * d0 + d1 * d1 + d2 * d2;
#pragma unroll
  for (int off = 32; off > 0; off >>= 1) s2 += __shfl_down(s2, off, 64);
  if ((tid & 63) == 0) red[4 + (tid >> 6)] = s2;
  __syncthreads();
  float rstd = rsqrtf((red[4] + red[5] + red[6] + red[7]) * (1.0f / 768.0f) + 1e-5f);
#pragma unroll
  for (int i = 0; i < 3; i++) {
    int d = tid + i * 256;
    h2[(size_t)t * Dn + d] = f2bf((xv[i] - mean) * rstd * g2[d] + be2[d]);
  }
}

// -- kernels 5/6: MFMA GEMM, BK=64 double-stage (round-8 staging), C = A*B^T ----
// GELU=true (fc1): tanh-exp GELU + single-pass LDS-coalesced bf16 epilogue.
// PARTIAL=true (fc2): round-8 direct stores, NO Cs (keeps VGPR 84 / LDS 32KB).
template <int KDIM, bool GELU, bool PARTIAL>
__global__ __launch_bounds__(256) void k_gemm(
    const ushort_t* __restrict__ A,   // [M][KDIM] bf16
    const ushort_t* __restrict__ Bw,  // [N][KDIM] bf16
    const float* __restrict__ bias,   // [N] fp32 (GELU only)
    ushort_t* __restrict__ CoutB,     // bf16 out
    float* __restrict__ CoutF,        // fp32 out
    int N)
{
  constexpr int SMEMN = GELU ? 17408 : 16384; // ushorts: max(staging, Cs) / staging
  __shared__ __align__(16) ushort_t smem[SMEMN];
  ushort_t* Asb[2] = { smem, smem + 8192 };
  ushort_t* Bsb[2] = { smem + 4096, smem + 12288 };
  ushort_t* Cs = smem;
  const int tid = threadIdx.x;
  const int m0 = blockIdx.y * 128, n0 = blockIdx.x * 128;
  const int wave = tid >> 6, lane = tid & 63;
  const int wm = (wave >> 1) << 6, wn = (wave & 1) << 6;
  const int lrow = lane & 15, quad = lane >> 4;
  const int lrow4 = lane >> 2, lcol8 = (lane & 3) * 8; // async staging coords

  f32x4 acc[4][4];
#pragma unroll
  for (int mi = 0; mi < 4; mi++)
#pragma unroll
    for (int ni = 0; ni < 4; ni++) acc[mi][ni] = (f32x4){0.f, 0.f, 0.f, 0.f};

  const int kbeg = PARTIAL ? blockIdx.z * (KDIM / 2) : 0;
  const int kend = kbeg + (PARTIAL ? KDIM / 2 : KDIM);

  for (int k0 = kbeg; k0 < kend; k0 += 64) {
#pragma unroll
    for (int t = 0; t < 2; t++) {
#pragma unroll
      for (int a = 0; a < 2; a++) {
        int rr = wave * 16 + a * 64;
        async_cp16(A + (size_t)(m0 + rr + lrow4) * KDIM + k0 + t * 32 + lcol8, Asb[t] + rr * 32);
        async_cp16(Bw + (size_t)(n0 + rr + lrow4) * KDIM + k0 + t * 32 + lcol8, Bsb[t] + rr * 32);
      }
    }
    __syncthreads();
#pragma unroll
    for (int t = 0; t < 2; t++) {
      short8 af[4], bfv[4];
#pragma unroll
      for (int mi = 0; mi < 4; mi++)
        af[mi] = *(const short8*)(Asb[t] + (wm + mi * 16 + lrow) * 32 + quad * 8);
#pragma unroll
      for (int ni = 0; ni < 4; ni++)
        bfv[ni] = *(const short8*)(Bsb[t] + (wn + ni * 16 + lrow) * 32 + quad * 8);
#pragma unroll
      for (int mi = 0; mi < 4; mi++)
#pragma unroll
        for (int ni = 0; ni < 4; ni++)
          acc[mi][ni] = __builtin_amdgcn_mfma_f32_16x16x32_bf16(af[mi], bfv[ni], acc[mi][ni], 0, 0, 0);
    }
    __syncthreads();
  }

  if (GELU) {
    // fc1: cheap tanh-exp GELU (max dev ~3e-4) + coalesced epilogue via Cs
#pragma unroll
    for (int ni = 0; ni < 4; ni++) {
      int col = wn + ni * 16 + lrow;
      float bc = bias[n0 + col];
#pragma unroll
      for (int mi = 0; mi < 4; mi++) {
#pragma unroll
        for (int r = 0; r < 4; r++) {
          float vv = acc[mi][ni][r] + bc;
          float u = vv * (0.7978845608f + 0.0356774081f * vv * vv);
          float o = vv / (1.0f + __expf(-2.0f * u));
          Cs[(wm + mi * 16 + quad * 4 + r) * 136 + col] = f2bf(o);
        }
      }
    }
    __syncthreads();
    int row = tid >> 1, part = tid & 1;
    const uint4* s = (const uint4*)(Cs + row * 136 + part * 64);
    uint4* d = (uint4*)(CoutB + (size_t)(m0 + row) * N + n0 + part * 64);
#pragma unroll
    for (int i = 0; i < 8; i++) d[i] = s[i];
  } else {
    // fc2 partials: direct stores (round-8 proven)
#pragma unroll
    for (int ni = 0; ni < 4; ni++) {
      int col = n0 + wn + ni * 16 + lrow;
#pragma unroll
      for (int mi = 0; mi < 4; mi++) {
#pragma unroll
        for (int r = 0; r < 4; r++) {
          int row = m0 + wm + mi * 16 + quad * 4 + r;
          float vv = acc[mi][ni][r];
          if (blockIdx.z == 0) CoutB[(size_t)row * N + col] = f2bf(vv);
          else                 CoutF[(size_t)row * N + col] = vv;
        }
      }
    }
  }
}

// ---------------- kernel 7: split-K reduce + bias + residual -------------------
__global__ __launch_bounds__(256) void k_reduce(
    const ushort_t* __restrict__ p0,  // bf16 partial [8192][768]
    const float* __restrict__ p1,     // fp32 partial (aliases out)
    const float* __restrict__ res,    // out1
    const float* __restrict__ bias,   // bm2 [768]
    float* __restrict__ out)
{
  int i4 = blockIdx.x * 256 + threadIdx.x;     // float4 index, 1572864 total
  int col4 = (i4 % 192) * 4;
  float4 o = ((const float4*)p1)[i4];
  float4 r = ((const float4*)res)[i4];
  ushort4 a = ((const ushort4*)p0)[i4];
  o.x += bf2f(a.x) + bias[col4 + 0] + r.x;
  o.y += bf2f(a.y) + bias[col4 + 1] + r.y;
  o.z += bf2f(a.z) + bias[col4 + 2] + r.z;
  o.w += bf2f(a.w) + bias[col4 + 3] + r.w;
  ((float4*)out)[i4] = o;
}

// ---------------- launch --------------------------------------------------------
extern "C" void kernel_launch(void* const* d_in, const int* in_sizes, int n_in,
                              void* d_out, int out_size, void* d_ws, size_t ws_size,
                              hipStream_t stream) {
  (void)in_sizes; (void)n_in; (void)out_size; (void)ws_size;
  const float* x   = (const float*)d_in[0];
  const float* g1  = (const float*)d_in[1];
  const float* be1 = (const float*)d_in[2];
  const float* Wq  = (const float*)d_in[3];
  const float* bq  = (const float*)d_in[4];
  const float* Wk  = (const float*)d_in[5];
  const float* bk  = (const float*)d_in[6];
  const float* Wv  = (const float*)d_in[7];
  const float* bv  = (const float*)d_in[8];
  const float* g2  = (const float*)d_in[9];
  const float* be2 = (const float*)d_in[10];
  const float* W1  = (const float*)d_in[11];
  const float* bm1 = (const float*)d_in[12];
  const float* W2  = (const float*)d_in[13];
  const float* bm2 = (const float*)d_in[14];
  float* outp = (float*)d_out;

  char* ws = (char*)d_ws;
  float*    out1 = (float*)ws;                   // [0, 25165824)
  ushort_t* hb   = (ushort_t*)ws;                // bf16 h, pre-attn only
  ushort_t* qb   = (ushort_t*)(ws + 25165824);
  ushort_t* kb   = (ushort_t*)(ws + 37748736);
  ushort_t* vtb  = (ushort_t*)(ws + 50331648);   // V transposed [bh][64][256]
  ushort_t* h2   = qb;                           // reuse q after attn
  ushort_t* p0   = qb;                           // fc2 bf16 partial after fc1
  ushort_t* mb   = (ushort_t*)(ws + 37748736);   // overlays k,vt
  ushort_t* Wc   = (ushort_t*)(ws + 88080384);
  ushort_t* W1b  = (ushort_t*)(ws + 88375296);
  ushort_t* W2b  = (ushort_t*)(ws + 93093888);
  float*    bcb  = (float*)(ws + 97812480);

  const int nW1 = MLPn * Dn; // 2359296
  k_pack_qkv<<<dim3(576), dim3(256), 0, stream>>>(Wq, Wk, Wv, bq, bk, bv, Wc, bcb);
  k_f2bf<<<dim3(nW1 / 4 / 256), dim3(256), 0, stream>>>(W1, W1b, nW1 / 4);
  k_f2bf<<<dim3(nW1 / 4 / 256), dim3(256), 0, stream>>>(W2, W2b, nW1 / 4);

  k_ln1<<<dim3(NT), dim3(256), 0, stream>>>(x, g1, be1, hb);
  k_qkv<<<dim3(Bn * Hn * 2), dim3(256), 0, stream>>>(hb, Wc, bcb, qb, kb, vtb);
  k_attn<<<dim3(Bn * Hn * 4), dim3(256), 0, stream>>>(qb, kb, vtb, x, out1);
  k_ln2<<<dim3(NT), dim3(256), 0, stream>>>(out1, g2, be2, h2);
  // fc1: [8192][768] x [3072][768]^T -> gelu -> mb bf16
  k_gemm<Dn, true, false><<<dim3(MLPn / 128, NT / 128, 1), dim3(256), 0, stream>>>(
      h2, W1b, bm1, mb, nullptr, MLPn);
  // fc2 split-K=2: z=0 -> p0 bf16 (qb region), z=1 -> fp32 partial in d_out
  k_gemm<MLPn, false, true><<<dim3(Dn / 128, NT / 128, 2), dim3(256), 0, stream>>>(
      mb, W2b, nullptr, p0, outp, Dn);
  k_reduce<<<dim3(NT * Dn / 4 / 256), dim3(256), 0, stream>>>(p0, outp, out1, bm2, outp);
}

// Round 11
// 319.414 us; speedup vs baseline: 1.0640x; 1.0583x over previous
//
#include <hip/hip_runtime.h>
#include <hip/hip_bf16.h>
#include <math.h>

// ViT block, B=32 S=256 D=768 H=12 HD=64 MLP=3072. fp32 I/O, bf16 MFMA inside.
//
// ws layout (total ~97.9 MB):
//   [0,        25165824)  out1 fp32 [8192][768] residual trunk; hb bf16 pre-attn
//   [25165824, 37748736)  q bf16 ; h2 bf16 after attn
//   [37748736, 50331648)  k  bf16             ; overlaid by mb after attn
//   [50331648, 62914560)  vt bf16 [B,H,64,S]  ; overlaid by mb after attn
//   [37748736, 88080384)  mb bf16 [8192][3072] gelu(fc1)
//   [88080384, 88375296)  Wc  bf16 [12][192][64] packed qkv weights
//   [88375296, 93093888)  W1b bf16 [3072][768]
//   [93093888, 97812480)  W2b bf16 [768][3072]
//   [97812480, 97821696)  bcb fp32 [12][192] packed qkv bias
//
// Journal notes baked in:
//  - SQ_LDS_BANK_CONFLICT == 4718592 is the async-DMA LDS-write burst, NOT frag
//    read conflicts (constant across swizzle/no-swizzle, r5/r8/r9). Don't chase it.
//  - fc1 is plateaued at ~83 us across 6 variants (r5-r10). Stop tuning it.
//  - r10: fc2 split-K=2 showed FETCH 161 MB (3x A-ideal) + 15 us reduce overhead
//    -> this round: no split-K, 64x128 tile, full K, fused bias+residual epilogue.

static constexpr int Bn = 32, Sn = 256, Dn = 768, Hn = 12, HDn = 64, MLPn = 3072;
static constexpr int NT = Bn * Sn; // 8192 tokens

typedef unsigned short ushort_t;
typedef unsigned int u32;
typedef __attribute__((ext_vector_type(8))) short short8; // 8 bf16 MFMA A/B frag
typedef __attribute__((ext_vector_type(4))) float f32x4;  // MFMA C/D frag

__device__ __forceinline__ float bf2f(ushort_t u) { return __uint_as_float(((u32)u) << 16); }
__device__ __forceinline__ ushort_t f2bf(float f) { // round-to-nearest-even
  u32 u = __float_as_uint(f);
  u += 0x7fffu + ((u >> 16) & 1u);
  return (ushort_t)(u >> 16);
}

// async global->LDS 16B per lane; LDS dest = wave-uniform base + lane*16 (m97/m104)
__device__ __forceinline__ void async_cp16(const ushort_t* g, ushort_t* l) {
  __builtin_amdgcn_global_load_lds(
      (const __attribute__((address_space(1))) u32*)g,
      (__attribute__((address_space(3))) u32*)l, 16, 0, 0);
}

// ---------------- kernel 0: all weight prep in ONE launch ----------------------
// blocks [0,576)        : pack Wq|Wk|Wv -> Wc bf16 [12][192][64] + bias -> bcb
// blocks [576,2880)     : W1 -> W1b bf16 (float4 vectorized)
// blocks [2880,5184)    : W2 -> W2b bf16
__global__ __launch_bounds__(256) void k_prep(
    const float* __restrict__ Wq, const float* __restrict__ Wk,
    const float* __restrict__ Wv, const float* __restrict__ bq,
    const float* __restrict__ bk, const float* __restrict__ bv,
    const float* __restrict__ W1, const float* __restrict__ W2,
    ushort_t* __restrict__ Wc, float* __restrict__ bc,
    ushort_t* __restrict__ W1b, ushort_t* __restrict__ W2b)
{
  const int bx = blockIdx.x;
  if (bx < 576) {
    int i = bx * 256 + threadIdx.x; // 0 .. 147455
    int h = i / 12288, rem = i - h * 12288;
    int mat = rem / 4096, w = rem - mat * 4096;
    const float* src = (mat == 0) ? Wq : ((mat == 1) ? Wk : Wv);
    Wc[i] = f2bf(src[h * 4096 + w]);
    if (i < Hn * 192) {
      int h2 = i / 192, r2 = i - h2 * 192;
      int m2 = r2 / 64, e2 = r2 - m2 * 64;
      const float* bs = (m2 == 0) ? bq : ((m2 == 1) ? bk : bv);
      bc[i] = bs[h2 * 64 + e2];
    }
  } else {
    int j = bx - 576;
    const float* src = (j < 2304) ? W1 : W2;
    ushort_t* dst = (j < 2304) ? W1b : W2b;
    int i = (j % 2304) * 256 + threadIdx.x; // float4 index < 589824
    float4 v = ((const float4*)src)[i];
    ushort4 o;
    o.x = f2bf(v.x); o.y = f2bf(v.y); o.z = f2bf(v.z); o.w = f2bf(v.w);
    ((ushort4*)dst)[i] = o;
  }
}

// ---------------- kernel 1: LN1 -> bf16 (one WG per token) ---------------------
__global__ __launch_bounds__(256) void k_ln1(
    const float* __restrict__ x, const float* __restrict__ g1,
    const float* __restrict__ be1, ushort_t* __restrict__ hb)
{
  const int t = blockIdx.x, tid = threadIdx.x;
  __shared__ float red[8];
  float xv[3];
#pragma unroll
  for (int i = 0; i < 3; i++) xv[i] = x[(size_t)t * Dn + tid + i * 256];
  float s = xv[0] + xv[1] + xv[2];
#pragma unroll
  for (int off = 32; off > 0; off >>= 1) s += __shfl_down(s, off, 64);
  if ((tid & 63) == 0) red[tid >> 6] = s;
  __syncthreads();
  float mean = (red[0] + red[1] + red[2] + red[3]) * (1.0f / 768.0f);
  float d0 = xv[0] - mean, d1 = xv[1] - mean, d2 = xv[2] - mean;
  float s2 = d0 * d0 + d1 * d1 + d2 * d2;
#pragma unroll
  for (int off = 32; off > 0; off >>= 1) s2 += __shfl_down(s2, off, 64);
  if ((tid & 63) == 0) red[4 + (tid >> 6)] = s2;
  __syncthreads();
  float rstd = rsqrtf((red[4] + red[5] + red[6] + red[7]) * (1.0f / 768.0f) + 1e-5f);
#pragma unroll
  for (int i = 0; i < 3; i++) {
    int d = tid + i * 256;
    hb[(size_t)t * Dn + d] = f2bf((xv[i] - mean) * rstd * g1[d] + be1[d]);
  }
}

// ---------------- kernel 2: QKV projection via MFMA ----------------------------
__global__ __launch_bounds__(256) void k_qkv(
    const ushort_t* __restrict__ hb,  // [NT][768] bf16
    const ushort_t* __restrict__ Wc,  // [12][192][64] bf16
    const float* __restrict__ bc,     // [12][192] fp32
    ushort_t* __restrict__ qo, ushort_t* __restrict__ ko, ushort_t* __restrict__ vt)
{
  __shared__ __align__(16) ushort_t As[128 * 72];
  __shared__ __align__(16) ushort_t Ws[192 * 72];
  const int blk = blockIdx.x;         // (b*12 + h)*2 + half
  const int half = blk & 1;
  const int bh = blk >> 1;
  const int b_ = bh / Hn, h_ = bh - b_ * Hn;
  const int tid = threadIdx.x;
  const int t0 = b_ * Sn + half * 128;

  { // stage A: 128 rows x 64 cols (head slice of hb)
    int row = tid >> 1, seg = (tid & 1) * 32;
    const uint4* g = (const uint4*)(hb + (size_t)(t0 + row) * Dn + h_ * 64 + seg);
    uint4* s = (uint4*)(As + row * 72 + seg);
    s[0] = g[0]; s[1] = g[1]; s[2] = g[2]; s[3] = g[3];
  }
  { // stage W: 192 rows x 64 cols, contiguous per head
    int rr = tid >> 2, seg = (tid & 3) * 16;
    const ushort_t* gw = Wc + h_ * 12288;
#pragma unroll
    for (int p = 0; p < 3; p++) {
      int R = p * 64 + rr;
      const uint4* g = (const uint4*)(gw + R * 64 + seg);
      uint4* s = (uint4*)(Ws + R * 72 + seg);
      s[0] = g[0]; s[1] = g[1];
    }
  }
  __syncthreads();

  const int wave = tid >> 6, lane = tid & 63;
  const int wm = (wave >> 1) * 64, wn = (wave & 1) * 96;
  const int lrow = lane & 15, quad = lane >> 4;

  f32x4 acc[4][6];
#pragma unroll
  for (int mi = 0; mi < 4; mi++)
#pragma unroll
    for (int ni = 0; ni < 6; ni++) acc[mi][ni] = (f32x4){0.f, 0.f, 0.f, 0.f};

#pragma unroll
  for (int kk = 0; kk < 2; kk++) {
    short8 af[4], wf[6];
#pragma unroll
    for (int mi = 0; mi < 4; mi++)
      af[mi] = *(const short8*)(As + (wm + mi * 16 + lrow) * 72 + kk * 32 + quad * 8);
#pragma unroll
    for (int ni = 0; ni < 6; ni++)
      wf[ni] = *(const short8*)(Ws + (wn + ni * 16 + lrow) * 72 + kk * 32 + quad * 8);
#pragma unroll
    for (int mi = 0; mi < 4; mi++)
#pragma unroll
      for (int ni = 0; ni < 6; ni++)
        acc[mi][ni] = __builtin_amdgcn_mfma_f32_16x16x32_bf16(af[mi], wf[ni], acc[mi][ni], 0, 0, 0);
  }

#pragma unroll
  for (int ni = 0; ni < 6; ni++) {
    int c = wn + ni * 16 + lrow;        // 0..191, mat uniform per (wave,ni)
    int mat = c >> 6, e = c & 63;
    float bb = bc[h_ * 192 + c];
    if (mat < 2) {
      ushort_t* dst = (mat == 0) ? qo : ko;
      size_t base = (((size_t)bh) * Sn + half * 128 + wm) * HDn + e;
#pragma unroll
      for (int mi = 0; mi < 4; mi++) {
#pragma unroll
        for (int r = 0; r < 4; r++) {
          int lr = mi * 16 + quad * 4 + r;
          dst[base + (size_t)lr * HDn] = f2bf(acc[mi][ni][r] + bb);
        }
      }
    } else {
      size_t rowb = ((size_t)bh * 64 + e) * Sn + half * 128 + wm + quad * 4;
#pragma unroll
      for (int mi = 0; mi < 4; mi++) {
        ushort4 pk;
        pk.x = f2bf(acc[mi][ni][0] + bb);
        pk.y = f2bf(acc[mi][ni][1] + bb);
        pk.z = f2bf(acc[mi][ni][2] + bb);
        pk.w = f2bf(acc[mi][ni][3] + bb);
        *(ushort4*)(vt + rowb + mi * 16) = pk;
      }
    }
  }
}

// ---------------- kernel 3: MFMA flash attention -------------------------------
__global__ __launch_bounds__(256) void k_attn(
    const ushort_t* __restrict__ q,   // [bh][s][64]
    const ushort_t* __restrict__ kg_, // [bh][s][64]
    const ushort_t* __restrict__ vt,  // [bh][e=64][s=256]
    const float* __restrict__ x,
    float* __restrict__ out1)
{
  __shared__ __align__(16) ushort_t Ks[64 * 72];
  __shared__ __align__(16) ushort_t Vts[64 * 264];
  __shared__ __align__(16) ushort_t Pw[4][16 * 72];
  const int blk = blockIdx.x;          // bh*4 + quarter
  const int qtr = blk & 3, bh = blk >> 2;
  const int b_ = bh / Hn, h_ = bh - b_ * Hn;
  const int tid = threadIdx.x, wave = tid >> 6, lane = tid & 63;
  const int lr16 = lane & 15, quad = lane >> 4;
  const int s0 = qtr * 64 + wave * 16;

  { // stage Vt whole head
    int r = tid >> 2, cseg = (tid & 3) * 64;
    const uint4* g = (const uint4*)(vt + ((size_t)bh * 64 + r) * Sn + cseg);
    uint4* s = (uint4*)(Vts + r * 264 + cseg);
#pragma unroll
    for (int i = 0; i < 8; i++) s[i] = g[i];
  }

  short8 qf[2];
  {
    const ushort_t* qg = q + ((size_t)bh * Sn + s0 + lr16) * HDn + quad * 8;
    qf[0] = *(const short8*)(qg);
    qf[1] = *(const short8*)(qg + 32);
  }

  f32x4 of[4];
#pragma unroll
  for (int et = 0; et < 4; et++) of[et] = (f32x4){0.f, 0.f, 0.f, 0.f};
  float mrow[4] = {-3.0e38f, -3.0e38f, -3.0e38f, -3.0e38f};
  float lsum[4] = {0.f, 0.f, 0.f, 0.f};

  const ushort_t* kgb = kg_ + (size_t)bh * Sn * HDn;

  for (int c = 0; c < 4; c++) {
    if (c) __syncthreads();
    {
      int row = tid >> 2, seg = (tid & 3) * 16;
      const uint4* g = (const uint4*)(kgb + (size_t)(c * 64 + row) * HDn + seg);
      uint4* s = (uint4*)(Ks + row * 72 + seg);
      s[0] = g[0]; s[1] = g[1];
    }
    __syncthreads();

    f32x4 sc[4];
#pragma unroll
    for (int ni = 0; ni < 4; ni++) sc[ni] = (f32x4){0.f, 0.f, 0.f, 0.f};
#pragma unroll
    for (int kk = 0; kk < 2; kk++) {
#pragma unroll
      for (int ni = 0; ni < 4; ni++) {
        short8 kf = *(const short8*)(Ks + (ni * 16 + lr16) * 72 + kk * 32 + quad * 8);
        sc[ni] = __builtin_amdgcn_mfma_f32_16x16x32_bf16(qf[kk], kf, sc[ni], 0, 0, 0);
      }
    }

    float alpha[4];
#pragma unroll
    for (int r = 0; r < 4; r++) {
      float m_ = fmaxf(fmaxf(sc[0][r], sc[1][r]), fmaxf(sc[2][r], sc[3][r]));
#pragma unroll
      for (int msk = 8; msk >= 1; msk >>= 1) m_ = fmaxf(m_, __shfl_xor(m_, msk, 64));
      float mn = fmaxf(mrow[r], m_);
      alpha[r] = __expf((mrow[r] - mn) * 0.125f);
      mrow[r] = mn;
    }
#pragma unroll
    for (int ni = 0; ni < 4; ni++) {
#pragma unroll
      for (int r = 0; r < 4; r++) {
        float p = __expf((sc[ni][r] - mrow[r]) * 0.125f);
        sc[ni][r] = p;
        Pw[wave][(quad * 4 + r) * 72 + ni * 16 + lr16] = f2bf(p);
      }
    }
#pragma unroll
    for (int r = 0; r < 4; r++) {
      float s_ = (sc[0][r] + sc[1][r]) + (sc[2][r] + sc[3][r]);
#pragma unroll
      for (int msk = 8; msk >= 1; msk >>= 1) s_ += __shfl_xor(s_, msk, 64);
      lsum[r] = lsum[r] * alpha[r] + s_;
    }
#pragma unroll
    for (int et = 0; et < 4; et++)
#pragma unroll
      for (int r = 0; r < 4; r++) of[et][r] *= alpha[r];

    short8 pf0 = *(const short8*)(&Pw[wave][lr16 * 72 + quad * 8]);
    short8 pf1 = *(const short8*)(&Pw[wave][lr16 * 72 + 32 + quad * 8]);
#pragma unroll
    for (int et = 0; et < 4; et++) {
      short8 vf0 = *(const short8*)(Vts + (et * 16 + lr16) * 264 + c * 64 + quad * 8);
      short8 vf1 = *(const short8*)(Vts + (et * 16 + lr16) * 264 + c * 64 + 32 + quad * 8);
      of[et] = __builtin_amdgcn_mfma_f32_16x16x32_bf16(pf0, vf0, of[et], 0, 0, 0);
      of[et] = __builtin_amdgcn_mfma_f32_16x16x32_bf16(pf1, vf1, of[et], 0, 0, 0);
    }
  }

  const size_t obase = ((size_t)b_ * Sn + s0) * Dn + h_ * 64;
#pragma unroll
  for (int r = 0; r < 4; r++) {
    float rl = 1.0f / lsum[r];
    int row = quad * 4 + r;
#pragma unroll
    for (int et = 0; et < 4; et++) {
      size_t idx = obase + (size_t)row * Dn + et * 16 + lr16;
      out1[idx] = of[et][r] * rl + x[idx];
    }
  }
}

// ---------------- kernel 4: LN2 (one WG per token) -----------------------------
__global__ __launch_bounds__(256) void k_ln2(
    const float* __restrict__ in, const float* __restrict__ g2,
    const float* __restrict__ be2, ushort_t* __restrict__ h2)
{
  const int t = blockIdx.x, tid = threadIdx.x;
  __shared__ float red[8];
  float xv[3];
#pragma unroll
  for (int i = 0; i < 3; i++) xv[i] = in[(size_t)t * Dn + tid + i * 256];
  float s = xv[0] + xv[1] + xv[2];
#pragma unroll
  for (int off = 32; off > 0; off >>= 1) s += __shfl_down(s, off, 64);
  if ((tid & 63) == 0) red[tid >> 6] = s;
  __syncthreads();
  float mean = (red[0] + red[1] + red[2] + red[3]) * (1.0f / 768.0f);
  float d0 = xv[0] - mean, d1 = xv[1] - mean, d2 = xv[2] - mean;
  float s2 = d0 * d0 + d1 * d1 + d2 * d2;
#pragma unroll
  for (int off = 32; off > 0; off >>= 1) s2 += __shfl_down(s2, off, 64);
  if ((tid & 63) == 0) red[4 + (tid >> 6)] = s2;
  __syncthreads();
  float rstd = rsqrtf((red[4] + red[5] + red[6] + red[7]) * (1.0f / 768.0f) + 1e-5f);
#pragma unroll
  for (int i = 0; i < 3; i++) {
    int d = tid + i * 256;
    h2[(size_t)t * Dn + d] = f2bf((xv[i] - mean) * rstd * g2[d] + be2[d]);
  }
}

// -------- kernel 5: fc1 MFMA GEMM, 128x128, BK=64 double-stage (r10) -----------
__global__ __launch_bounds__(256) void k_gemm1(
    const ushort_t* __restrict__ A,   // h2 [8192][768] bf16
    const ushort_t* __restrict__ Bw,  // W1b [3072][768] bf16
    const float* __restrict__ bias,   // bm1 [3072]
    ushort_t* __restrict__ CoutB)     // mb [8192][3072] bf16
{
  constexpr int KDIM = Dn, N = MLPn;
  __shared__ __align__(16) ushort_t smem[17408]; // staging 32KB / Cs 128x136
  ushort_t* Asb[2] = { smem, smem + 8192 };
  ushort_t* Bsb[2] = { smem + 4096, smem + 12288 };
  ushort_t* Cs = smem;
  const int tid = threadIdx.x;
  const int m0 = blockIdx.y * 128, n0 = blockIdx.x * 128;
  const int wave = tid >> 6, lane = tid & 63;
  const int wm = (wave >> 1) << 6, wn = (wave & 1) << 6;
  const int lrow = lane & 15, quad = lane >> 4;
  const int lrow4 = lane >> 2, lcol8 = (lane & 3) * 8;

  f32x4 acc[4][4];
#pragma unroll
  for (int mi = 0; mi < 4; mi++)
#pragma unroll
    for (int ni = 0; ni < 4; ni++) acc[mi][ni] = (f32x4){0.f, 0.f, 0.f, 0.f};

  for (int k0 = 0; k0 < KDIM; k0 += 64) {
#pragma unroll
    for (int t = 0; t < 2; t++) {
#pragma unroll
      for (int a = 0; a < 2; a++) {
        int rr = wave * 16 + a * 64;
        async_cp16(A + (size_t)(m0 + rr + lrow4) * KDIM + k0 + t * 32 + lcol8, Asb[t] + rr * 32);
        async_cp16(Bw + (size_t)(n0 + rr + lrow4) * KDIM + k0 + t * 32 + lcol8, Bsb[t] + rr * 32);
      }
    }
    __syncthreads();
#pragma unroll
    for (int t = 0; t < 2; t++) {
      short8 af[4], bfv[4];
#pragma unroll
      for (int mi = 0; mi < 4; mi++)
        af[mi] = *(const short8*)(Asb[t] + (wm + mi * 16 + lrow) * 32 + quad * 8);
#pragma unroll
      for (int ni = 0; ni < 4; ni++)
        bfv[ni] = *(const short8*)(Bsb[t] + (wn + ni * 16 + lrow) * 32 + quad * 8);
#pragma unroll
      for (int mi = 0; mi < 4; mi++)
#pragma unroll
        for (int ni = 0; ni < 4; ni++)
          acc[mi][ni] = __builtin_amdgcn_mfma_f32_16x16x32_bf16(af[mi], bfv[ni], acc[mi][ni], 0, 0, 0);
    }
    __syncthreads();
  }

  // tanh-exp GELU + single-pass LDS-coalesced bf16 epilogue
#pragma unroll
  for (int ni = 0; ni < 4; ni++) {
    int col = wn + ni * 16 + lrow;
    float bc = bias[n0 + col];
#pragma unroll
    for (int mi = 0; mi < 4; mi++) {
#pragma unroll
      for (int r = 0; r < 4; r++) {
        float vv = acc[mi][ni][r] + bc;
        float u = vv * (0.7978845608f + 0.0356774081f * vv * vv);
        float o = vv / (1.0f + __expf(-2.0f * u));
        Cs[(wm + mi * 16 + quad * 4 + r) * 136 + col] = f2bf(o);
      }
    }
  }
  __syncthreads();
  int row = tid >> 1, part = tid & 1;
  const uint4* s = (const uint4*)(Cs + row * 136 + part * 64);
  uint4* d = (uint4*)(CoutB + (size_t)(m0 + row) * N + n0 + part * 64);
#pragma unroll
  for (int i = 0; i < 8; i++) d[i] = s[i];
}

// -------- kernel 6: fc2 MFMA GEMM, 64x128 tile, full K, fused epilogue ---------
// grid (6, 128): m0 = by*64, n0 = bx*128. 768 blocks, K=3072 (48 BK64 iters).
// Wave = 32x64 (2x4 frags). Epilogue: + bm2 + out1 residual -> fp32 d_out.
__global__ __launch_bounds__(256) void k_gemm2(
    const ushort_t* __restrict__ A,   // mb [8192][3072] bf16
    const ushort_t* __restrict__ Bw,  // W2b [768][3072] bf16
    const float* __restrict__ bias,   // bm2 [768]
    const float* __restrict__ res,    // out1 [8192][768] fp32
    float* __restrict__ out)          // d_out [8192][768] fp32
{
  constexpr int KDIM = MLPn, N = Dn;
  __shared__ __align__(16) ushort_t As[2][64 * 32];   // 8 KB
  __shared__ __align__(16) ushort_t Bs[2][128 * 32];  // 16 KB
  const int tid = threadIdx.x;
  const int m0 = blockIdx.y * 64, n0 = blockIdx.x * 128;
  const int wave = tid >> 6, lane = tid & 63;
  const int wm = (wave >> 1) << 5, wn = (wave & 1) << 6; // 32-row, 64-col wave tile
  const int lrow = lane & 15, quad = lane >> 4;
  const int lrow4 = lane >> 2, lcol8 = (lane & 3) * 8;

  f32x4 acc[2][4];
#pragma unroll
  for (int mi = 0; mi < 2; mi++)
#pragma unroll
    for (int ni = 0; ni < 4; ni++) acc[mi][ni] = (f32x4){0.f, 0.f, 0.f, 0.f};

  for (int k0 = 0; k0 < KDIM; k0 += 64) {
#pragma unroll
    for (int t = 0; t < 2; t++) {
      int rr = wave * 16;
      async_cp16(A + (size_t)(m0 + rr + lrow4) * KDIM + k0 + t * 32 + lcol8, As[t] + rr * 32);
#pragma unroll
      for (int a = 0; a < 2; a++) {
        int rb = rr + a * 64;
        async_cp16(Bw + (size_t)(n0 + rb + lrow4) * KDIM + k0 + t * 32 + lcol8, Bs[t] + rb * 32);
      }
    }
    __syncthreads();
#pragma unroll
    for (int t = 0; t < 2; t++) {
      short8 af[2], bfv[4];
#pragma unroll
      for (int mi = 0; mi < 2; mi++)
        af[mi] = *(const short8*)(As[t] + (wm + mi * 16 + lrow) * 32 + quad * 8);
#pragma unroll
      for (int ni = 0; ni < 4; ni++)
        bfv[ni] = *(const short8*)(Bs[t] + (wn + ni * 16 + lrow) * 32 + quad * 8);
#pragma unroll
      for (int mi = 0; mi < 2; mi++)
#pragma unroll
        for (int ni = 0; ni < 4; ni++)
          acc[mi][ni] = __builtin_amdgcn_mfma_f32_16x16x32_bf16(af[mi], bfv[ni], acc[mi][ni], 0, 0, 0);
    }
    __syncthreads();
  }

  // fused epilogue: + bias + residual -> fp32 (16-lane x 4B = full 64B segments)
#pragma unroll
  for (int ni = 0; ni < 4; ni++) {
    int col = n0 + wn + ni * 16 + lrow;
    float bc = bias[col];
#pragma unroll
    for (int mi = 0; mi < 2; mi++) {
#pragma unroll
      for (int r = 0; r < 4; r++) {
        int row = m0 + wm + mi * 16 + quad * 4 + r;
        size_t idx = (size_t)row * N + col;
        out[idx] = acc[mi][ni][r] + bc + res[idx];
      }
    }
  }
}

// ---------------- launch --------------------------------------------------------
extern "C" void kernel_launch(void* const* d_in, const int* in_sizes, int n_in,
                              void* d_out, int out_size, void* d_ws, size_t ws_size,
                              hipStream_t stream) {
  (void)in_sizes; (void)n_in; (void)out_size; (void)ws_size;
  const float* x   = (const float*)d_in[0];
  const float* g1  = (const float*)d_in[1];
  const float* be1 = (const float*)d_in[2];
  const float* Wq  = (const float*)d_in[3];
  const float* bq  = (const float*)d_in[4];
  const float* Wk  = (const float*)d_in[5];
  const float* bk  = (const float*)d_in[6];
  const float* Wv  = (const float*)d_in[7];
  const float* bv  = (const float*)d_in[8];
  const float* g2  = (const float*)d_in[9];
  const float* be2 = (const float*)d_in[10];
  const float* W1  = (const float*)d_in[11];
  const float* bm1 = (const float*)d_in[12];
  const float* W2  = (const float*)d_in[13];
  const float* bm2 = (const float*)d_in[14];
  float* outp = (float*)d_out;

  char* ws = (char*)d_ws;
  float*    out1 = (float*)ws;                   // [0, 25165824)
  ushort_t* hb   = (ushort_t*)ws;                // bf16 h, pre-attn only
  ushort_t* qb   = (ushort_t*)(ws + 25165824);
  ushort_t* kb   = (ushort_t*)(ws + 37748736);
  ushort_t* vtb  = (ushort_t*)(ws + 50331648);   // V transposed [bh][64][256]
  ushort_t* h2   = qb;                           // reuse q after attn
  ushort_t* mb   = (ushort_t*)(ws + 37748736);   // overlays k,vt
  ushort_t* Wc   = (ushort_t*)(ws + 88080384);
  ushort_t* W1b  = (ushort_t*)(ws + 88375296);
  ushort_t* W2b  = (ushort_t*)(ws + 93093888);
  float*    bcb  = (float*)(ws + 97812480);

  k_prep<<<dim3(5184), dim3(256), 0, stream>>>(Wq, Wk, Wv, bq, bk, bv, W1, W2,
                                               Wc, bcb, W1b, W2b);
  k_ln1<<<dim3(NT), dim3(256), 0, stream>>>(x, g1, be1, hb);
  k_qkv<<<dim3(Bn * Hn * 2), dim3(256), 0, stream>>>(hb, Wc, bcb, qb, kb, vtb);
  k_attn<<<dim3(Bn * Hn * 4), dim3(256), 0, stream>>>(qb, kb, vtb, x, out1);
  k_ln2<<<dim3(NT), dim3(256), 0, stream>>>(out1, g2, be2, h2);
  k_gemm1<<<dim3(MLPn / 128, NT / 128), dim3(256), 0, stream>>>(h2, W1b, bm1, mb);
  k_gemm2<<<dim3(Dn / 128, NT / 64), dim3(256), 0, stream>>>(mb, W2b, bm2, out1, outp);
}

// Round 12
// 312.177 us; speedup vs baseline: 1.0886x; 1.0232x over previous
//
#include <hip/hip_runtime.h>
#include <hip/hip_bf16.h>
#include <math.h>

// ViT block, B=32 S=256 D=768 H=12 HD=64 MLP=3072. fp32 I/O, bf16 MFMA inside.
//
// ws layout (total ~97.9 MB):
//   [0,        25165824)  out1 fp32 [8192][768] residual trunk; hb bf16 pre-attn
//   [25165824, 37748736)  q bf16 ; h2 bf16 after attn
//   [37748736, 50331648)  k  bf16             ; overlaid by mb after attn
//   [50331648, 62914560)  vt bf16 [B,H,64,S]  ; overlaid by mb after attn
//   [37748736, 88080384)  mb bf16 [8192][3072] gelu(fc1)
//   [88080384, 88375296)  Wc  bf16 [12][192][64] packed qkv weights
//   [88375296, 93093888)  W1b bf16 [3072][768]
//   [93093888, 97812480)  W2b bf16 [768][3072]
//   [97812480, 97821696)  bcb fp32 [12][192] packed qkv bias
//
// Journal notes baked in:
//  - SQ_LDS_BANK_CONFLICT == 4718592 is the async-DMA LDS-write burst, NOT frag
//    read conflicts (constant across swizzle/no-swizzle, r5/r8/r9). Don't chase it.
//  - r10 fc2 rebuild (64x128, full K, fused +bias+residual) beat split-K; reduce gone.
//  - r12: fc1 was latency/barrier-bound at 20% occupancy (2 blk/CU, 18432
//    barrier-iters). This round: 512-thr 256x128 tile -> 9216 barrier-iters,
//    16 waves/CU. Per-thread shape (64x64 wave tile, VGPR ~88) unchanged.

static constexpr int Bn = 32, Sn = 256, Dn = 768, Hn = 12, HDn = 64, MLPn = 3072;
static constexpr int NT = Bn * Sn; // 8192 tokens

typedef unsigned short ushort_t;
typedef unsigned int u32;
typedef __attribute__((ext_vector_type(8))) short short8; // 8 bf16 MFMA A/B frag
typedef __attribute__((ext_vector_type(4))) float f32x4;  // MFMA C/D frag

__device__ __forceinline__ float bf2f(ushort_t u) { return __uint_as_float(((u32)u) << 16); }
__device__ __forceinline__ ushort_t f2bf(float f) { // round-to-nearest-even
  u32 u = __float_as_uint(f);
  u += 0x7fffu + ((u >> 16) & 1u);
  return (ushort_t)(u >> 16);
}

// async global->LDS 16B per lane; LDS dest = wave-uniform base + lane*16 (m97/m104)
__device__ __forceinline__ void async_cp16(const ushort_t* g, ushort_t* l) {
  __builtin_amdgcn_global_load_lds(
      (const __attribute__((address_space(1))) u32*)g,
      (__attribute__((address_space(3))) u32*)l, 16, 0, 0);
}

// ---------------- kernel 0: all weight prep in ONE launch ----------------------
__global__ __launch_bounds__(256) void k_prep(
    const float* __restrict__ Wq, const float* __restrict__ Wk,
    const float* __restrict__ Wv, const float* __restrict__ bq,
    const float* __restrict__ bk, const float* __restrict__ bv,
    const float* __restrict__ W1, const float* __restrict__ W2,
    ushort_t* __restrict__ Wc, float* __restrict__ bc,
    ushort_t* __restrict__ W1b, ushort_t* __restrict__ W2b)
{
  const int bx = blockIdx.x;
  if (bx < 576) {
    int i = bx * 256 + threadIdx.x; // 0 .. 147455
    int h = i / 12288, rem = i - h * 12288;
    int mat = rem / 4096, w = rem - mat * 4096;
    const float* src = (mat == 0) ? Wq : ((mat == 1) ? Wk : Wv);
    Wc[i] = f2bf(src[h * 4096 + w]);
    if (i < Hn * 192) {
      int h2 = i / 192, r2 = i - h2 * 192;
      int m2 = r2 / 64, e2 = r2 - m2 * 64;
      const float* bs = (m2 == 0) ? bq : ((m2 == 1) ? bk : bv);
      bc[i] = bs[h2 * 64 + e2];
    }
  } else {
    int j = bx - 576;
    const float* src = (j < 2304) ? W1 : W2;
    ushort_t* dst = (j < 2304) ? W1b : W2b;
    int i = (j % 2304) * 256 + threadIdx.x; // float4 index < 589824
    float4 v = ((const float4*)src)[i];
    ushort4 o;
    o.x = f2bf(v.x); o.y = f2bf(v.y); o.z = f2bf(v.z); o.w = f2bf(v.w);
    ((ushort4*)dst)[i] = o;
  }
}

// ---------------- kernel 1: LN1 -> bf16 (one WG per token) ---------------------
__global__ __launch_bounds__(256) void k_ln1(
    const float* __restrict__ x, const float* __restrict__ g1,
    const float* __restrict__ be1, ushort_t* __restrict__ hb)
{
  const int t = blockIdx.x, tid = threadIdx.x;
  __shared__ float red[8];
  float xv[3];
#pragma unroll
  for (int i = 0; i < 3; i++) xv[i] = x[(size_t)t * Dn + tid + i * 256];
  float s = xv[0] + xv[1] + xv[2];
#pragma unroll
  for (int off = 32; off > 0; off >>= 1) s += __shfl_down(s, off, 64);
  if ((tid & 63) == 0) red[tid >> 6] = s;
  __syncthreads();
  float mean = (red[0] + red[1] + red[2] + red[3]) * (1.0f / 768.0f);
  float d0 = xv[0] - mean, d1 = xv[1] - mean, d2 = xv[2] - mean;
  float s2 = d0 * d0 + d1 * d1 + d2 * d2;
#pragma unroll
  for (int off = 32; off > 0; off >>= 1) s2 += __shfl_down(s2, off, 64);
  if ((tid & 63) == 0) red[4 + (tid >> 6)] = s2;
  __syncthreads();
  float rstd = rsqrtf((red[4] + red[5] + red[6] + red[7]) * (1.0f / 768.0f) + 1e-5f);
#pragma unroll
  for (int i = 0; i < 3; i++) {
    int d = tid + i * 256;
    hb[(size_t)t * Dn + d] = f2bf((xv[i] - mean) * rstd * g1[d] + be1[d]);
  }
}

// ---------------- kernel 2: QKV projection via MFMA ----------------------------
__global__ __launch_bounds__(256) void k_qkv(
    const ushort_t* __restrict__ hb,  // [NT][768] bf16
    const ushort_t* __restrict__ Wc,  // [12][192][64] bf16
    const float* __restrict__ bc,     // [12][192] fp32
    ushort_t* __restrict__ qo, ushort_t* __restrict__ ko, ushort_t* __restrict__ vt)
{
  __shared__ __align__(16) ushort_t As[128 * 72];
  __shared__ __align__(16) ushort_t Ws[192 * 72];
  const int blk = blockIdx.x;         // (b*12 + h)*2 + half
  const int half = blk & 1;
  const int bh = blk >> 1;
  const int b_ = bh / Hn, h_ = bh - b_ * Hn;
  const int tid = threadIdx.x;
  const int t0 = b_ * Sn + half * 128;

  { // stage A: 128 rows x 64 cols (head slice of hb)
    int row = tid >> 1, seg = (tid & 1) * 32;
    const uint4* g = (const uint4*)(hb + (size_t)(t0 + row) * Dn + h_ * 64 + seg);
    uint4* s = (uint4*)(As + row * 72 + seg);
    s[0] = g[0]; s[1] = g[1]; s[2] = g[2]; s[3] = g[3];
  }
  { // stage W: 192 rows x 64 cols, contiguous per head
    int rr = tid >> 2, seg = (tid & 3) * 16;
    const ushort_t* gw = Wc + h_ * 12288;
#pragma unroll
    for (int p = 0; p < 3; p++) {
      int R = p * 64 + rr;
      const uint4* g = (const uint4*)(gw + R * 64 + seg);
      uint4* s = (uint4*)(Ws + R * 72 + seg);
      s[0] = g[0]; s[1] = g[1];
    }
  }
  __syncthreads();

  const int wave = tid >> 6, lane = tid & 63;
  const int wm = (wave >> 1) * 64, wn = (wave & 1) * 96;
  const int lrow = lane & 15, quad = lane >> 4;

  f32x4 acc[4][6];
#pragma unroll
  for (int mi = 0; mi < 4; mi++)
#pragma unroll
    for (int ni = 0; ni < 6; ni++) acc[mi][ni] = (f32x4){0.f, 0.f, 0.f, 0.f};

#pragma unroll
  for (int kk = 0; kk < 2; kk++) {
    short8 af[4], wf[6];
#pragma unroll
    for (int mi = 0; mi < 4; mi++)
      af[mi] = *(const short8*)(As + (wm + mi * 16 + lrow) * 72 + kk * 32 + quad * 8);
#pragma unroll
    for (int ni = 0; ni < 6; ni++)
      wf[ni] = *(const short8*)(Ws + (wn + ni * 16 + lrow) * 72 + kk * 32 + quad * 8);
#pragma unroll
    for (int mi = 0; mi < 4; mi++)
#pragma unroll
      for (int ni = 0; ni < 6; ni++)
        acc[mi][ni] = __builtin_amdgcn_mfma_f32_16x16x32_bf16(af[mi], wf[ni], acc[mi][ni], 0, 0, 0);
  }

#pragma unroll
  for (int ni = 0; ni < 6; ni++) {
    int c = wn + ni * 16 + lrow;        // 0..191, mat uniform per (wave,ni)
    int mat = c >> 6, e = c & 63;
    float bb = bc[h_ * 192 + c];
    if (mat < 2) {
      ushort_t* dst = (mat == 0) ? qo : ko;
      size_t base = (((size_t)bh) * Sn + half * 128 + wm) * HDn + e;
#pragma unroll
      for (int mi = 0; mi < 4; mi++) {
#pragma unroll
        for (int r = 0; r < 4; r++) {
          int lr = mi * 16 + quad * 4 + r;
          dst[base + (size_t)lr * HDn] = f2bf(acc[mi][ni][r] + bb);
        }
      }
    } else {
      size_t rowb = ((size_t)bh * 64 + e) * Sn + half * 128 + wm + quad * 4;
#pragma unroll
      for (int mi = 0; mi < 4; mi++) {
        ushort4 pk;
        pk.x = f2bf(acc[mi][ni][0] + bb);
        pk.y = f2bf(acc[mi][ni][1] + bb);
        pk.z = f2bf(acc[mi][ni][2] + bb);
        pk.w = f2bf(acc[mi][ni][3] + bb);
        *(ushort4*)(vt + rowb + mi * 16) = pk;
      }
    }
  }
}

// ---------------- kernel 3: MFMA flash attention -------------------------------
__global__ __launch_bounds__(256) void k_attn(
    const ushort_t* __restrict__ q,   // [bh][s][64]
    const ushort_t* __restrict__ kg_, // [bh][s][64]
    const ushort_t* __restrict__ vt,  // [bh][e=64][s=256]
    const float* __restrict__ x,
    float* __restrict__ out1)
{
  __shared__ __align__(16) ushort_t Ks[64 * 72];
  __shared__ __align__(16) ushort_t Vts[64 * 264];
  __shared__ __align__(16) ushort_t Pw[4][16 * 72];
  const int blk = blockIdx.x;          // bh*4 + quarter
  const int qtr = blk & 3, bh = blk >> 2;
  const int b_ = bh / Hn, h_ = bh - b_ * Hn;
  const int tid = threadIdx.x, wave = tid >> 6, lane = tid & 63;
  const int lr16 = lane & 15, quad = lane >> 4;
  const int s0 = qtr * 64 + wave * 16;

  { // stage Vt whole head
    int r = tid >> 2, cseg = (tid & 3) * 64;
    const uint4* g = (const uint4*)(vt + ((size_t)bh * 64 + r) * Sn + cseg);
    uint4* s = (uint4*)(Vts + r * 264 + cseg);
#pragma unroll
    for (int i = 0; i < 8; i++) s[i] = g[i];
  }

  short8 qf[2];
  {
    const ushort_t* qg = q + ((size_t)bh * Sn + s0 + lr16) * HDn + quad * 8;
    qf[0] = *(const short8*)(qg);
    qf[1] = *(const short8*)(qg + 32);
  }

  f32x4 of[4];
#pragma unroll
  for (int et = 0; et < 4; et++) of[et] = (f32x4){0.f, 0.f, 0.f, 0.f};
  float mrow[4] = {-3.0e38f, -3.0e38f, -3.0e38f, -3.0e38f};
  float lsum[4] = {0.f, 0.f, 0.f, 0.f};

  const ushort_t* kgb = kg_ + (size_t)bh * Sn * HDn;

  for (int c = 0; c < 4; c++) {
    if (c) __syncthreads();
    {
      int row = tid >> 2, seg = (tid & 3) * 16;
      const uint4* g = (const uint4*)(kgb + (size_t)(c * 64 + row) * HDn + seg);
      uint4* s = (uint4*)(Ks + row * 72 + seg);
      s[0] = g[0]; s[1] = g[1];
    }
    __syncthreads();

    f32x4 sc[4];
#pragma unroll
    for (int ni = 0; ni < 4; ni++) sc[ni] = (f32x4){0.f, 0.f, 0.f, 0.f};
#pragma unroll
    for (int kk = 0; kk < 2; kk++) {
#pragma unroll
      for (int ni = 0; ni < 4; ni++) {
        short8 kf = *(const short8*)(Ks + (ni * 16 + lr16) * 72 + kk * 32 + quad * 8);
        sc[ni] = __builtin_amdgcn_mfma_f32_16x16x32_bf16(qf[kk], kf, sc[ni], 0, 0, 0);
      }
    }

    float alpha[4];
#pragma unroll
    for (int r = 0; r < 4; r++) {
      float m_ = fmaxf(fmaxf(sc[0][r], sc[1][r]), fmaxf(sc[2][r], sc[3][r]));
#pragma unroll
      for (int msk = 8; msk >= 1; msk >>= 1) m_ = fmaxf(m_, __shfl_xor(m_, msk, 64));
      float mn = fmaxf(mrow[r], m_);
      alpha[r] = __expf((mrow[r] - mn) * 0.125f);
      mrow[r] = mn;
    }
#pragma unroll
    for (int ni = 0; ni < 4; ni++) {
#pragma unroll
      for (int r = 0; r < 4; r++) {
        float p = __expf((sc[ni][r] - mrow[r]) * 0.125f);
        sc[ni][r] = p;
        Pw[wave][(quad * 4 + r) * 72 + ni * 16 + lr16] = f2bf(p);
      }
    }
#pragma unroll
    for (int r = 0; r < 4; r++) {
      float s_ = (sc[0][r] + sc[1][r]) + (sc[2][r] + sc[3][r]);
#pragma unroll
      for (int msk = 8; msk >= 1; msk >>= 1) s_ += __shfl_xor(s_, msk, 64);
      lsum[r] = lsum[r] * alpha[r] + s_;
    }
#pragma unroll
    for (int et = 0; et < 4; et++)
#pragma unroll
      for (int r = 0; r < 4; r++) of[et][r] *= alpha[r];

    short8 pf0 = *(const short8*)(&Pw[wave][lr16 * 72 + quad * 8]);
    short8 pf1 = *(const short8*)(&Pw[wave][lr16 * 72 + 32 + quad * 8]);
#pragma unroll
    for (int et = 0; et < 4; et++) {
      short8 vf0 = *(const short8*)(Vts + (et * 16 + lr16) * 264 + c * 64 + quad * 8);
      short8 vf1 = *(const short8*)(Vts + (et * 16 + lr16) * 264 + c * 64 + 32 + quad * 8);
      of[et] = __builtin_amdgcn_mfma_f32_16x16x32_bf16(pf0, vf0, of[et], 0, 0, 0);
      of[et] = __builtin_amdgcn_mfma_f32_16x16x32_bf16(pf1, vf1, of[et], 0, 0, 0);
    }
  }

  const size_t obase = ((size_t)b_ * Sn + s0) * Dn + h_ * 64;
#pragma unroll
  for (int r = 0; r < 4; r++) {
    float rl = 1.0f / lsum[r];
    int row = quad * 4 + r;
#pragma unroll
    for (int et = 0; et < 4; et++) {
      size_t idx = obase + (size_t)row * Dn + et * 16 + lr16;
      out1[idx] = of[et][r] * rl + x[idx];
    }
  }
}

// ---------------- kernel 4: LN2 (one WG per token) -----------------------------
__global__ __launch_bounds__(256) void k_ln2(
    const float* __restrict__ in, const float* __restrict__ g2,
    const float* __restrict__ be2, ushort_t* __restrict__ h2)
{
  const int t = blockIdx.x, tid = threadIdx.x;
  __shared__ float red[8];
  float xv[3];
#pragma unroll
  for (int i = 0; i < 3; i++) xv[i] = in[(size_t)t * Dn + tid + i * 256];
  float s = xv[0] + xv[1] + xv[2];
#pragma unroll
  for (int off = 32; off > 0; off >>= 1) s += __shfl_down(s, off, 64);
  if ((tid & 63) == 0) red[tid >> 6] = s;
  __syncthreads();
  float mean = (red[0] + red[1] + red[2] + red[3]) * (1.0f / 768.0f);
  float d0 = xv[0] - mean, d1 = xv[1] - mean, d2 = xv[2] - mean;
  float s2 = d0 * d0 + d1 * d1 + d2 * d2;
#pragma unroll
  for (int off = 32; off > 0; off >>= 1) s2 += __shfl_down(s2, off, 64);
  if ((tid & 63) == 0) red[4 + (tid >> 6)] = s2;
  __syncthreads();
  float rstd = rsqrtf((red[4] + red[5] + red[6] + red[7]) * (1.0f / 768.0f) + 1e-5f);
#pragma unroll
  for (int i = 0; i < 3; i++) {
    int d = tid + i * 256;
    h2[(size_t)t * Dn + d] = f2bf((xv[i] - mean) * rstd * g2[d] + be2[d]);
  }
}

// ---- kernel 5: fc1 MFMA GEMM, 512 threads, 256x128 tile, BK=64 double-stage ---
// 8 waves 4(m)x2(n), each wave the proven 64x64 4x4-frag shape (VGPR ~88).
// LDS: staging 48KB (As 2x256x32 + Bs 2x128x32) unioned under Cs 256x136 (69.6KB)
// -> 2 blocks/CU (VGPR cap 16 waves/CU). Barrier-iters halve vs 256-thr version.
__global__ __launch_bounds__(512) void k_gemm1(
    const ushort_t* __restrict__ A,   // h2 [8192][768] bf16
    const ushort_t* __restrict__ Bw,  // W1b [3072][768] bf16
    const float* __restrict__ bias,   // bm1 [3072]
    ushort_t* __restrict__ CoutB)     // mb [8192][3072] bf16
{
  constexpr int KDIM = Dn, N = MLPn;
  __shared__ __align__(16) ushort_t smem[256 * 136]; // 69.6KB: Cs ⊇ staging 24576
  ushort_t* Asb[2] = { smem, smem + 12288 };          // each 256*32 = 8192
  ushort_t* Bsb[2] = { smem + 8192, smem + 20480 };   // each 128*32 = 4096
  ushort_t* Cs = smem;
  const int tid = threadIdx.x;
  const int m0 = blockIdx.y * 256, n0 = blockIdx.x * 128;
  const int wave = tid >> 6, lane = tid & 63;         // wave 0..7
  const int wm = (wave >> 1) << 6, wn = (wave & 1) << 6; // wm 0..192, wn 0/64
  const int lrow = lane & 15, quad = lane >> 4;
  const int lrow4 = lane >> 2, lcol8 = (lane & 3) * 8;

  f32x4 acc[4][4];
#pragma unroll
  for (int mi = 0; mi < 4; mi++)
#pragma unroll
    for (int ni = 0; ni < 4; ni++) acc[mi][ni] = (f32x4){0.f, 0.f, 0.f, 0.f};

  for (int k0 = 0; k0 < KDIM; k0 += 64) {
#pragma unroll
    for (int t = 0; t < 2; t++) {
      // A: 256 rows = 16 groups of 16; wave stages groups {wave, wave+8}
      async_cp16(A + (size_t)(m0 + wave * 16 + lrow4) * KDIM + k0 + t * 32 + lcol8,
                 Asb[t] + (wave * 16) * 32);
      async_cp16(A + (size_t)(m0 + 128 + wave * 16 + lrow4) * KDIM + k0 + t * 32 + lcol8,
                 Asb[t] + (128 + wave * 16) * 32);
      // B: 128 rows = 8 groups; wave stages group {wave}
      async_cp16(Bw + (size_t)(n0 + wave * 16 + lrow4) * KDIM + k0 + t * 32 + lcol8,
                 Bsb[t] + (wave * 16) * 32);
    }
    __syncthreads();
#pragma unroll
    for (int t = 0; t < 2; t++) {
      short8 af[4], bfv[4];
#pragma unroll
      for (int mi = 0; mi < 4; mi++)
        af[mi] = *(const short8*)(Asb[t] + (wm + mi * 16 + lrow) * 32 + quad * 8);
#pragma unroll
      for (int ni = 0; ni < 4; ni++)
        bfv[ni] = *(const short8*)(Bsb[t] + (wn + ni * 16 + lrow) * 32 + quad * 8);
#pragma unroll
      for (int mi = 0; mi < 4; mi++)
#pragma unroll
        for (int ni = 0; ni < 4; ni++)
          acc[mi][ni] = __builtin_amdgcn_mfma_f32_16x16x32_bf16(af[mi], bfv[ni], acc[mi][ni], 0, 0, 0);
    }
    __syncthreads();
  }

  // tanh-exp GELU + single-pass LDS-coalesced bf16 epilogue (all 8 waves deposit)
#pragma unroll
  for (int ni = 0; ni < 4; ni++) {
    int col = wn + ni * 16 + lrow;
    float bc = bias[n0 + col];
#pragma unroll
    for (int mi = 0; mi < 4; mi++) {
#pragma unroll
      for (int r = 0; r < 4; r++) {
        float vv = acc[mi][ni][r] + bc;
        float u = vv * (0.7978845608f + 0.0356774081f * vv * vv);
        float o = vv / (1.0f + __expf(-2.0f * u));
        Cs[(wm + mi * 16 + quad * 4 + r) * 136 + col] = f2bf(o);
      }
    }
  }
  __syncthreads();
  int row = tid >> 1, part = tid & 1;   // 512 threads -> 256 rows x 2 halves
  const uint4* s = (const uint4*)(Cs + row * 136 + part * 64);
  uint4* d = (uint4*)(CoutB + (size_t)(m0 + row) * N + n0 + part * 64);
#pragma unroll
  for (int i = 0; i < 8; i++) d[i] = s[i];
}

// -------- kernel 6: fc2 MFMA GEMM, 64x128 tile, full K, fused epilogue ---------
__global__ __launch_bounds__(256) void k_gemm2(
    const ushort_t* __restrict__ A,   // mb [8192][3072] bf16
    const ushort_t* __restrict__ Bw,  // W2b [768][3072] bf16
    const float* __restrict__ bias,   // bm2 [768]
    const float* __restrict__ res,    // out1 [8192][768] fp32
    float* __restrict__ out)          // d_out [8192][768] fp32
{
  constexpr int KDIM = MLPn, N = Dn;
  __shared__ __align__(16) ushort_t As[2][64 * 32];   // 8 KB
  __shared__ __align__(16) ushort_t Bs[2][128 * 32];  // 16 KB
  const int tid = threadIdx.x;
  const int m0 = blockIdx.y * 64, n0 = blockIdx.x * 128;
  const int wave = tid >> 6, lane = tid & 63;
  const int wm = (wave >> 1) << 5, wn = (wave & 1) << 6; // 32-row, 64-col wave tile
  const int lrow = lane & 15, quad = lane >> 4;
  const int lrow4 = lane >> 2, lcol8 = (lane & 3) * 8;

  f32x4 acc[2][4];
#pragma unroll
  for (int mi = 0; mi < 2; mi++)
#pragma unroll
    for (int ni = 0; ni < 4; ni++) acc[mi][ni] = (f32x4){0.f, 0.f, 0.f, 0.f};

  for (int k0 = 0; k0 < KDIM; k0 += 64) {
#pragma unroll
    for (int t = 0; t < 2; t++) {
      int rr = wave * 16;
      async_cp16(A + (size_t)(m0 + rr + lrow4) * KDIM + k0 + t * 32 + lcol8, As[t] + rr * 32);
#pragma unroll
      for (int a = 0; a < 2; a++) {
        int rb = rr + a * 64;
        async_cp16(Bw + (size_t)(n0 + rb + lrow4) * KDIM + k0 + t * 32 + lcol8, Bs[t] + rb * 32);
      }
    }
    __syncthreads();
#pragma unroll
    for (int t = 0; t < 2; t++) {
      short8 af[2], bfv[4];
#pragma unroll
      for (int mi = 0; mi < 2; mi++)
        af[mi] = *(const short8*)(As[t] + (wm + mi * 16 + lrow) * 32 + quad * 8);
#pragma unroll
      for (int ni = 0; ni < 4; ni++)
        bfv[ni] = *(const short8*)(Bs[t] + (wn + ni * 16 + lrow) * 32 + quad * 8);
#pragma unroll
      for (int mi = 0; mi < 2; mi++)
#pragma unroll
        for (int ni = 0; ni < 4; ni++)
          acc[mi][ni] = __builtin_amdgcn_mfma_f32_16x16x32_bf16(af[mi], bfv[ni], acc[mi][ni], 0, 0, 0);
    }
    __syncthreads();
  }

  // fused epilogue: + bias + residual -> fp32 (16-lane x 4B = full 64B segments)
#pragma unroll
  for (int ni = 0; ni < 4; ni++) {
    int col = n0 + wn + ni * 16 + lrow;
    float bc = bias[col];
#pragma unroll
    for (int mi = 0; mi < 2; mi++) {
#pragma unroll
      for (int r = 0; r < 4; r++) {
        int row = m0 + wm + mi * 16 + quad * 4 + r;
        size_t idx = (size_t)row * N + col;
        out[idx] = acc[mi][ni][r] + bc + res[idx];
      }
    }
  }
}

// ---------------- launch --------------------------------------------------------
extern "C" void kernel_launch(void* const* d_in, const int* in_sizes, int n_in,
                              void* d_out, int out_size, void* d_ws, size_t ws_size,
                              hipStream_t stream) {
  (void)in_sizes; (void)n_in; (void)out_size; (void)ws_size;
  const float* x   = (const float*)d_in[0];
  const float* g1  = (const float*)d_in[1];
  const float* be1 = (const float*)d_in[2];
  const float* Wq  = (const float*)d_in[3];
  const float* bq  = (const float*)d_in[4];
  const float* Wk  = (const float*)d_in[5];
  const float* bk  = (const float*)d_in[6];
  const float* Wv  = (const float*)d_in[7];
  const float* bv  = (const float*)d_in[8];
  const float* g2  = (const float*)d_in[9];
  const float* be2 = (const float*)d_in[10];
  const float* W1  = (const float*)d_in[11];
  const float* bm1 = (const float*)d_in[12];
  const float* W2  = (const float*)d_in[13];
  const float* bm2 = (const float*)d_in[14];
  float* outp = (float*)d_out;

  char* ws = (char*)d_ws;
  float*    out1 = (float*)ws;                   // [0, 25165824)
  ushort_t* hb   = (ushort_t*)ws;                // bf16 h, pre-attn only
  ushort_t* qb   = (ushort_t*)(ws + 25165824);
  ushort_t* kb   = (ushort_t*)(ws + 37748736);
  ushort_t* vtb  = (ushort_t*)(ws + 50331648);   // V transposed [bh][64][256]
  ushort_t* h2   = qb;                           // reuse q after attn
  ushort_t* mb   = (ushort_t*)(ws + 37748736);   // overlays k,vt
  ushort_t* Wc   = (ushort_t*)(ws + 88080384);
  ushort_t* W1b  = (ushort_t*)(ws + 88375296);
  ushort_t* W2b  = (ushort_t*)(ws + 93093888);
  float*    bcb  = (float*)(ws + 97812480);

  k_prep<<<dim3(5184), dim3(256), 0, stream>>>(Wq, Wk, Wv, bq, bk, bv, W1, W2,
                                               Wc, bcb, W1b, W2b);
  k_ln1<<<dim3(NT), dim3(256), 0, stream>>>(x, g1, be1, hb);
  k_qkv<<<dim3(Bn * Hn * 2), dim3(256), 0, stream>>>(hb, Wc, bcb, qb, kb, vtb);
  k_attn<<<dim3(Bn * Hn * 4), dim3(256), 0, stream>>>(qb, kb, vtb, x, out1);
  k_ln2<<<dim3(NT), dim3(256), 0, stream>>>(out1, g2, be2, h2);
  k_gemm1<<<dim3(MLPn / 128, NT / 256), dim3(512), 0, stream>>>(h2, W1b, bm1, mb);
  k_gemm2<<<dim3(Dn / 128, NT / 64), dim3(256), 0, stream>>>(mb, W2b, bm2, out1, outp);
}

// Round 13
// 298.260 us; speedup vs baseline: 1.1394x; 1.0467x over previous
//
#include <hip/hip_runtime.h>
#include <hip/hip_bf16.h>
#include <math.h>

// ViT block, B=32 S=256 D=768 H=12 HD=64 MLP=3072. fp32 I/O, bf16 MFMA inside.
//
// ws layout (total ~97.9 MB):
//   [0,        25165824)  out1 fp32 [8192][768] residual trunk; hb bf16 pre-attn
//   [25165824, 37748736)  q bf16 ; h2 bf16 after attn
//   [37748736, 50331648)  k  bf16             ; overlaid by mb after attn
//   [50331648, 62914560)  vt bf16 [B,H,64,S]  ; overlaid by mb after attn
//   [37748736, 88080384)  mb bf16 [8192][3072] gelu(fc1)
//   [88080384, 88375296)  Wc  bf16 [12][192][64] packed qkv weights
//   [88375296, 93093888)  W1b bf16 [3072][768]
//   [93093888, 97812480)  W2b bf16 [768][3072]
//   [97812480, 97821696)  bcb fp32 [12][192] packed qkv bias
//
// Journal notes baked in:
//  - SQ_LDS_BANK_CONFLICT ~4.7M/7.1M is the async-DMA LDS-write burst, NOT frag
//    read conflicts (constant across swizzle/no-swizzle, r5/r8/r9). Don't chase it.
//  - r12: 512-thr 256x128 fc1 (16 waves/CU) beat the 82us plateau.
//  - r13: fc2 FETCH was 175 MB vs 80 ideal -- consecutive blocks sharing an A
//    row-tile round-robin onto different XCDs, duplicating the tile in every L2.
//    Fix: XCD-aware swizzle (xcd = b&7 owns a contiguous row-tile band; columns
//    iterate fastest within an XCD). Same for fc1 (58 MB vs 17 ideal).

static constexpr int Bn = 32, Sn = 256, Dn = 768, Hn = 12, HDn = 64, MLPn = 3072;
static constexpr int NT = Bn * Sn; // 8192 tokens

typedef unsigned short ushort_t;
typedef unsigned int u32;
typedef __attribute__((ext_vector_type(8))) short short8; // 8 bf16 MFMA A/B frag
typedef __attribute__((ext_vector_type(4))) float f32x4;  // MFMA C/D frag

__device__ __forceinline__ float bf2f(ushort_t u) { return __uint_as_float(((u32)u) << 16); }
__device__ __forceinline__ ushort_t f2bf(float f) { // round-to-nearest-even
  u32 u = __float_as_uint(f);
  u += 0x7fffu + ((u >> 16) & 1u);
  return (ushort_t)(u >> 16);
}

// async global->LDS 16B per lane; LDS dest = wave-uniform base + lane*16 (m97/m104)
__device__ __forceinline__ void async_cp16(const ushort_t* g, ushort_t* l) {
  __builtin_amdgcn_global_load_lds(
      (const __attribute__((address_space(1))) u32*)g,
      (__attribute__((address_space(3))) u32*)l, 16, 0, 0);
}

// ---------------- kernel 0: all weight prep in ONE launch ----------------------
__global__ __launch_bounds__(256) void k_prep(
    const float* __restrict__ Wq, const float* __restrict__ Wk,
    const float* __restrict__ Wv, const float* __restrict__ bq,
    const float* __restrict__ bk, const float* __restrict__ bv,
    const float* __restrict__ W1, const float* __restrict__ W2,
    ushort_t* __restrict__ Wc, float* __restrict__ bc,
    ushort_t* __restrict__ W1b, ushort_t* __restrict__ W2b)
{
  const int bx = blockIdx.x;
  if (bx < 576) {
    int i = bx * 256 + threadIdx.x; // 0 .. 147455
    int h = i / 12288, rem = i - h * 12288;
    int mat = rem / 4096, w = rem - mat * 4096;
    const float* src = (mat == 0) ? Wq : ((mat == 1) ? Wk : Wv);
    Wc[i] = f2bf(src[h * 4096 + w]);
    if (i < Hn * 192) {
      int h2 = i / 192, r2 = i - h2 * 192;
      int m2 = r2 / 64, e2 = r2 - m2 * 64;
      const float* bs = (m2 == 0) ? bq : ((m2 == 1) ? bk : bv);
      bc[i] = bs[h2 * 64 + e2];
    }
  } else {
    int j = bx - 576;
    const float* src = (j < 2304) ? W1 : W2;
    ushort_t* dst = (j < 2304) ? W1b : W2b;
    int i = (j % 2304) * 256 + threadIdx.x; // float4 index < 589824
    float4 v = ((const float4*)src)[i];
    ushort4 o;
    o.x = f2bf(v.x); o.y = f2bf(v.y); o.z = f2bf(v.z); o.w = f2bf(v.w);
    ((ushort4*)dst)[i] = o;
  }
}

// ---------------- kernel 1: LN1 -> bf16 (one WG per token) ---------------------
__global__ __launch_bounds__(256) void k_ln1(
    const float* __restrict__ x, const float* __restrict__ g1,
    const float* __restrict__ be1, ushort_t* __restrict__ hb)
{
  const int t = blockIdx.x, tid = threadIdx.x;
  __shared__ float red[8];
  float xv[3];
#pragma unroll
  for (int i = 0; i < 3; i++) xv[i] = x[(size_t)t * Dn + tid + i * 256];
  float s = xv[0] + xv[1] + xv[2];
#pragma unroll
  for (int off = 32; off > 0; off >>= 1) s += __shfl_down(s, off, 64);
  if ((tid & 63) == 0) red[tid >> 6] = s;
  __syncthreads();
  float mean = (red[0] + red[1] + red[2] + red[3]) * (1.0f / 768.0f);
  float d0 = xv[0] - mean, d1 = xv[1] - mean, d2 = xv[2] - mean;
  float s2 = d0 * d0 + d1 * d1 + d2 * d2;
#pragma unroll
  for (int off = 32; off > 0; off >>= 1) s2 += __shfl_down(s2, off, 64);
  if ((tid & 63) == 0) red[4 + (tid >> 6)] = s2;
  __syncthreads();
  float rstd = rsqrtf((red[4] + red[5] + red[6] + red[7]) * (1.0f / 768.0f) + 1e-5f);
#pragma unroll
  for (int i = 0; i < 3; i++) {
    int d = tid + i * 256;
    hb[(size_t)t * Dn + d] = f2bf((xv[i] - mean) * rstd * g1[d] + be1[d]);
  }
}

// ---------------- kernel 2: QKV projection via MFMA ----------------------------
__global__ __launch_bounds__(256) void k_qkv(
    const ushort_t* __restrict__ hb,  // [NT][768] bf16
    const ushort_t* __restrict__ Wc,  // [12][192][64] bf16
    const float* __restrict__ bc,     // [12][192] fp32
    ushort_t* __restrict__ qo, ushort_t* __restrict__ ko, ushort_t* __restrict__ vt)
{
  __shared__ __align__(16) ushort_t As[128 * 72];
  __shared__ __align__(16) ushort_t Ws[192 * 72];
  const int blk = blockIdx.x;         // (b*12 + h)*2 + half
  const int half = blk & 1;
  const int bh = blk >> 1;
  const int b_ = bh / Hn, h_ = bh - b_ * Hn;
  const int tid = threadIdx.x;
  const int t0 = b_ * Sn + half * 128;

  { // stage A: 128 rows x 64 cols (head slice of hb)
    int row = tid >> 1, seg = (tid & 1) * 32;
    const uint4* g = (const uint4*)(hb + (size_t)(t0 + row) * Dn + h_ * 64 + seg);
    uint4* s = (uint4*)(As + row * 72 + seg);
    s[0] = g[0]; s[1] = g[1]; s[2] = g[2]; s[3] = g[3];
  }
  { // stage W: 192 rows x 64 cols, contiguous per head
    int rr = tid >> 2, seg = (tid & 3) * 16;
    const ushort_t* gw = Wc + h_ * 12288;
#pragma unroll
    for (int p = 0; p < 3; p++) {
      int R = p * 64 + rr;
      const uint4* g = (const uint4*)(gw + R * 64 + seg);
      uint4* s = (uint4*)(Ws + R * 72 + seg);
      s[0] = g[0]; s[1] = g[1];
    }
  }
  __syncthreads();

  const int wave = tid >> 6, lane = tid & 63;
  const int wm = (wave >> 1) * 64, wn = (wave & 1) * 96;
  const int lrow = lane & 15, quad = lane >> 4;

  f32x4 acc[4][6];
#pragma unroll
  for (int mi = 0; mi < 4; mi++)
#pragma unroll
    for (int ni = 0; ni < 6; ni++) acc[mi][ni] = (f32x4){0.f, 0.f, 0.f, 0.f};

#pragma unroll
  for (int kk = 0; kk < 2; kk++) {
    short8 af[4], wf[6];
#pragma unroll
    for (int mi = 0; mi < 4; mi++)
      af[mi] = *(const short8*)(As + (wm + mi * 16 + lrow) * 72 + kk * 32 + quad * 8);
#pragma unroll
    for (int ni = 0; ni < 6; ni++)
      wf[ni] = *(const short8*)(Ws + (wn + ni * 16 + lrow) * 72 + kk * 32 + quad * 8);
#pragma unroll
    for (int mi = 0; mi < 4; mi++)
#pragma unroll
      for (int ni = 0; ni < 6; ni++)
        acc[mi][ni] = __builtin_amdgcn_mfma_f32_16x16x32_bf16(af[mi], wf[ni], acc[mi][ni], 0, 0, 0);
  }

#pragma unroll
  for (int ni = 0; ni < 6; ni++) {
    int c = wn + ni * 16 + lrow;        // 0..191, mat uniform per (wave,ni)
    int mat = c >> 6, e = c & 63;
    float bb = bc[h_ * 192 + c];
    if (mat < 2) {
      ushort_t* dst = (mat == 0) ? qo : ko;
      size_t base = (((size_t)bh) * Sn + half * 128 + wm) * HDn + e;
#pragma unroll
      for (int mi = 0; mi < 4; mi++) {
#pragma unroll
        for (int r = 0; r < 4; r++) {
          int lr = mi * 16 + quad * 4 + r;
          dst[base + (size_t)lr * HDn] = f2bf(acc[mi][ni][r] + bb);
        }
      }
    } else {
      size_t rowb = ((size_t)bh * 64 + e) * Sn + half * 128 + wm + quad * 4;
#pragma unroll
      for (int mi = 0; mi < 4; mi++) {
        ushort4 pk;
        pk.x = f2bf(acc[mi][ni][0] + bb);
        pk.y = f2bf(acc[mi][ni][1] + bb);
        pk.z = f2bf(acc[mi][ni][2] + bb);
        pk.w = f2bf(acc[mi][ni][3] + bb);
        *(ushort4*)(vt + rowb + mi * 16) = pk;
      }
    }
  }
}

// ---------------- kernel 3: MFMA flash attention -------------------------------
__global__ __launch_bounds__(256) void k_attn(
    const ushort_t* __restrict__ q,   // [bh][s][64]
    const ushort_t* __restrict__ kg_, // [bh][s][64]
    const ushort_t* __restrict__ vt,  // [bh][e=64][s=256]
    const float* __restrict__ x,
    float* __restrict__ out1)
{
  __shared__ __align__(16) ushort_t Ks[64 * 72];
  __shared__ __align__(16) ushort_t Vts[64 * 264];
  __shared__ __align__(16) ushort_t Pw[4][16 * 72];
  const int blk = blockIdx.x;          // bh*4 + quarter
  const int qtr = blk & 3, bh = blk >> 2;
  const int b_ = bh / Hn, h_ = bh - b_ * Hn;
  const int tid = threadIdx.x, wave = tid >> 6, lane = tid & 63;
  const int lr16 = lane & 15, quad = lane >> 4;
  const int s0 = qtr * 64 + wave * 16;

  { // stage Vt whole head
    int r = tid >> 2, cseg = (tid & 3) * 64;
    const uint4* g = (const uint4*)(vt + ((size_t)bh * 64 + r) * Sn + cseg);
    uint4* s = (uint4*)(Vts + r * 264 + cseg);
#pragma unroll
    for (int i = 0; i < 8; i++) s[i] = g[i];
  }

  short8 qf[2];
  {
    const ushort_t* qg = q + ((size_t)bh * Sn + s0 + lr16) * HDn + quad * 8;
    qf[0] = *(const short8*)(qg);
    qf[1] = *(const short8*)(qg + 32);
  }

  f32x4 of[4];
#pragma unroll
  for (int et = 0; et < 4; et++) of[et] = (f32x4){0.f, 0.f, 0.f, 0.f};
  float mrow[4] = {-3.0e38f, -3.0e38f, -3.0e38f, -3.0e38f};
  float lsum[4] = {0.f, 0.f, 0.f, 0.f};

  const ushort_t* kgb = kg_ + (size_t)bh * Sn * HDn;

  for (int c = 0; c < 4; c++) {
    if (c) __syncthreads();
    {
      int row = tid >> 2, seg = (tid & 3) * 16;
      const uint4* g = (const uint4*)(kgb + (size_t)(c * 64 + row) * HDn + seg);
      uint4* s = (uint4*)(Ks + row * 72 + seg);
      s[0] = g[0]; s[1] = g[1];
    }
    __syncthreads();

    f32x4 sc[4];
#pragma unroll
    for (int ni = 0; ni < 4; ni++) sc[ni] = (f32x4){0.f, 0.f, 0.f, 0.f};
#pragma unroll
    for (int kk = 0; kk < 2; kk++) {
#pragma unroll
      for (int ni = 0; ni < 4; ni++) {
        short8 kf = *(const short8*)(Ks + (ni * 16 + lr16) * 72 + kk * 32 + quad * 8);
        sc[ni] = __builtin_amdgcn_mfma_f32_16x16x32_bf16(qf[kk], kf, sc[ni], 0, 0, 0);
      }
    }

    float alpha[4];
#pragma unroll
    for (int r = 0; r < 4; r++) {
      float m_ = fmaxf(fmaxf(sc[0][r], sc[1][r]), fmaxf(sc[2][r], sc[3][r]));
#pragma unroll
      for (int msk = 8; msk >= 1; msk >>= 1) m_ = fmaxf(m_, __shfl_xor(m_, msk, 64));
      float mn = fmaxf(mrow[r], m_);
      alpha[r] = __expf((mrow[r] - mn) * 0.125f);
      mrow[r] = mn;
    }
#pragma unroll
    for (int ni = 0; ni < 4; ni++) {
#pragma unroll
      for (int r = 0; r < 4; r++) {
        float p = __expf((sc[ni][r] - mrow[r]) * 0.125f);
        sc[ni][r] = p;
        Pw[wave][(quad * 4 + r) * 72 + ni * 16 + lr16] = f2bf(p);
      }
    }
#pragma unroll
    for (int r = 0; r < 4; r++) {
      float s_ = (sc[0][r] + sc[1][r]) + (sc[2][r] + sc[3][r]);
#pragma unroll
      for (int msk = 8; msk >= 1; msk >>= 1) s_ += __shfl_xor(s_, msk, 64);
      lsum[r] = lsum[r] * alpha[r] + s_;
    }
#pragma unroll
    for (int et = 0; et < 4; et++)
#pragma unroll
      for (int r = 0; r < 4; r++) of[et][r] *= alpha[r];

    short8 pf0 = *(const short8*)(&Pw[wave][lr16 * 72 + quad * 8]);
    short8 pf1 = *(const short8*)(&Pw[wave][lr16 * 72 + 32 + quad * 8]);
#pragma unroll
    for (int et = 0; et < 4; et++) {
      short8 vf0 = *(const short8*)(Vts + (et * 16 + lr16) * 264 + c * 64 + quad * 8);
      short8 vf1 = *(const short8*)(Vts + (et * 16 + lr16) * 264 + c * 64 + 32 + quad * 8);
      of[et] = __builtin_amdgcn_mfma_f32_16x16x32_bf16(pf0, vf0, of[et], 0, 0, 0);
      of[et] = __builtin_amdgcn_mfma_f32_16x16x32_bf16(pf1, vf1, of[et], 0, 0, 0);
    }
  }

  const size_t obase = ((size_t)b_ * Sn + s0) * Dn + h_ * 64;
#pragma unroll
  for (int r = 0; r < 4; r++) {
    float rl = 1.0f / lsum[r];
    int row = quad * 4 + r;
#pragma unroll
    for (int et = 0; et < 4; et++) {
      size_t idx = obase + (size_t)row * Dn + et * 16 + lr16;
      out1[idx] = of[et][r] * rl + x[idx];
    }
  }
}

// ---------------- kernel 4: LN2 (one WG per token) -----------------------------
__global__ __launch_bounds__(256) void k_ln2(
    const float* __restrict__ in, const float* __restrict__ g2,
    const float* __restrict__ be2, ushort_t* __restrict__ h2)
{
  const int t = blockIdx.x, tid = threadIdx.x;
  __shared__ float red[8];
  float xv[3];
#pragma unroll
  for (int i = 0; i < 3; i++) xv[i] = in[(size_t)t * Dn + tid + i * 256];
  float s = xv[0] + xv[1] + xv[2];
#pragma unroll
  for (int off = 32; off > 0; off >>= 1) s += __shfl_down(s, off, 64);
  if ((tid & 63) == 0) red[tid >> 6] = s;
  __syncthreads();
  float mean = (red[0] + red[1] + red[2] + red[3]) * (1.0f / 768.0f);
  float d0 = xv[0] - mean, d1 = xv[1] - mean, d2 = xv[2] - mean;
  float s2 = d0 * d0 + d1 * d1 + d2 * d2;
#pragma unroll
  for (int off = 32; off > 0; off >>= 1) s2 += __shfl_down(s2, off, 64);
  if ((tid & 63) == 0) red[4 + (tid >> 6)] = s2;
  __syncthreads();
  float rstd = rsqrtf((red[4] + red[5] + red[6] + red[7]) * (1.0f / 768.0f) + 1e-5f);
#pragma unroll
  for (int i = 0; i < 3; i++) {
    int d = tid + i * 256;
    h2[(size_t)t * Dn + d] = f2bf((xv[i] - mean) * rstd * g2[d] + be2[d]);
  }
}

// ---- kernel 5: fc1 MFMA GEMM, 512 threads, 256x128 tile, XCD-swizzled grid ----
// 1D grid 768: xcd = b&7 owns row-tiles [xcd*4, xcd*4+4), columns iterate fastest
// -> all 24 blocks sharing an A row-tile run on ONE XCD (A-tile hits its L2).
__global__ __launch_bounds__(512) void k_gemm1(
    const ushort_t* __restrict__ A,   // h2 [8192][768] bf16
    const ushort_t* __restrict__ Bw,  // W1b [3072][768] bf16
    const float* __restrict__ bias,   // bm1 [3072]
    ushort_t* __restrict__ CoutB)     // mb [8192][3072] bf16
{
  constexpr int KDIM = Dn, N = MLPn;
  __shared__ __align__(16) ushort_t smem[256 * 136]; // 69.6KB: Cs ⊇ staging 24576
  ushort_t* Asb[2] = { smem, smem + 12288 };          // each 256*32 = 8192
  ushort_t* Bsb[2] = { smem + 8192, smem + 20480 };   // each 128*32 = 4096
  ushort_t* Cs = smem;
  const int b = blockIdx.x;
  const int xcd = b & 7, slot = b >> 3;   // 96 slots per XCD
  const int cc = slot % 24, rloc = slot / 24;
  const int m0 = (xcd * 4 + rloc) * 256, n0 = cc * 128;
  const int tid = threadIdx.x;
  const int wave = tid >> 6, lane = tid & 63;         // wave 0..7
  const int wm = (wave >> 1) << 6, wn = (wave & 1) << 6;
  const int lrow = lane & 15, quad = lane >> 4;
  const int lrow4 = lane >> 2, lcol8 = (lane & 3) * 8;

  f32x4 acc[4][4];
#pragma unroll
  for (int mi = 0; mi < 4; mi++)
#pragma unroll
    for (int ni = 0; ni < 4; ni++) acc[mi][ni] = (f32x4){0.f, 0.f, 0.f, 0.f};

  for (int k0 = 0; k0 < KDIM; k0 += 64) {
#pragma unroll
    for (int t = 0; t < 2; t++) {
      async_cp16(A + (size_t)(m0 + wave * 16 + lrow4) * KDIM + k0 + t * 32 + lcol8,
                 Asb[t] + (wave * 16) * 32);
      async_cp16(A + (size_t)(m0 + 128 + wave * 16 + lrow4) * KDIM + k0 + t * 32 + lcol8,
                 Asb[t] + (128 + wave * 16) * 32);
      async_cp16(Bw + (size_t)(n0 + wave * 16 + lrow4) * KDIM + k0 + t * 32 + lcol8,
                 Bsb[t] + (wave * 16) * 32);
    }
    __syncthreads();
#pragma unroll
    for (int t = 0; t < 2; t++) {
      short8 af[4], bfv[4];
#pragma unroll
      for (int mi = 0; mi < 4; mi++)
        af[mi] = *(const short8*)(Asb[t] + (wm + mi * 16 + lrow) * 32 + quad * 8);
#pragma unroll
      for (int ni = 0; ni < 4; ni++)
        bfv[ni] = *(const short8*)(Bsb[t] + (wn + ni * 16 + lrow) * 32 + quad * 8);
#pragma unroll
      for (int mi = 0; mi < 4; mi++)
#pragma unroll
        for (int ni = 0; ni < 4; ni++)
          acc[mi][ni] = __builtin_amdgcn_mfma_f32_16x16x32_bf16(af[mi], bfv[ni], acc[mi][ni], 0, 0, 0);
    }
    __syncthreads();
  }

  // tanh-exp GELU + single-pass LDS-coalesced bf16 epilogue (all 8 waves deposit)
#pragma unroll
  for (int ni = 0; ni < 4; ni++) {
    int col = wn + ni * 16 + lrow;
    float bc = bias[n0 + col];
#pragma unroll
    for (int mi = 0; mi < 4; mi++) {
#pragma unroll
      for (int r = 0; r < 4; r++) {
        float vv = acc[mi][ni][r] + bc;
        float u = vv * (0.7978845608f + 0.0356774081f * vv * vv);
        float o = vv / (1.0f + __expf(-2.0f * u));
        Cs[(wm + mi * 16 + quad * 4 + r) * 136 + col] = f2bf(o);
      }
    }
  }
  __syncthreads();
  int row = tid >> 1, part = tid & 1;   // 512 threads -> 256 rows x 2 halves
  const uint4* s = (const uint4*)(Cs + row * 136 + part * 64);
  uint4* d = (uint4*)(CoutB + (size_t)(m0 + row) * N + n0 + part * 64);
#pragma unroll
  for (int i = 0; i < 8; i++) d[i] = s[i];
}

// ---- kernel 6: fc2 MFMA GEMM, 64x128 tile, full K, XCD-swizzled grid ----------
// 1D grid 768: xcd = b&7 owns row-tiles [xcd*16, xcd*16+16), columns fastest
// -> the 6 blocks sharing an A row-tile colocate on one XCD.
__global__ __launch_bounds__(256) void k_gemm2(
    const ushort_t* __restrict__ A,   // mb [8192][3072] bf16
    const ushort_t* __restrict__ Bw,  // W2b [768][3072] bf16
    const float* __restrict__ bias,   // bm2 [768]
    const float* __restrict__ res,    // out1 [8192][768] fp32
    float* __restrict__ out)          // d_out [8192][768] fp32
{
  constexpr int KDIM = MLPn, N = Dn;
  __shared__ __align__(16) ushort_t As[2][64 * 32];   // 8 KB
  __shared__ __align__(16) ushort_t Bs[2][128 * 32];  // 16 KB
  const int b = blockIdx.x;
  const int xcd = b & 7, slot = b >> 3;   // 96 slots per XCD
  const int cc = slot % 6, rloc = slot / 6;
  const int m0 = (xcd * 16 + rloc) * 64, n0 = cc * 128;
  const int tid = threadIdx.x;
  const int wave = tid >> 6, lane = tid & 63;
  const int wm = (wave >> 1) << 5, wn = (wave & 1) << 6; // 32-row, 64-col wave tile
  const int lrow = lane & 15, quad = lane >> 4;
  const int lrow4 = lane >> 2, lcol8 = (lane & 3) * 8;

  f32x4 acc[2][4];
#pragma unroll
  for (int mi = 0; mi < 2; mi++)
#pragma unroll
    for (int ni = 0; ni < 4; ni++) acc[mi][ni] = (f32x4){0.f, 0.f, 0.f, 0.f};

  for (int k0 = 0; k0 < KDIM; k0 += 64) {
#pragma unroll
    for (int t = 0; t < 2; t++) {
      int rr = wave * 16;
      async_cp16(A + (size_t)(m0 + rr + lrow4) * KDIM + k0 + t * 32 + lcol8, As[t] + rr * 32);
#pragma unroll
      for (int a = 0; a < 2; a++) {
        int rb = rr + a * 64;
        async_cp16(Bw + (size_t)(n0 + rb + lrow4) * KDIM + k0 + t * 32 + lcol8, Bs[t] + rb * 32);
      }
    }
    __syncthreads();
#pragma unroll
    for (int t = 0; t < 2; t++) {
      short8 af[2], bfv[4];
#pragma unroll
      for (int mi = 0; mi < 2; mi++)
        af[mi] = *(const short8*)(As[t] + (wm + mi * 16 + lrow) * 32 + quad * 8);
#pragma unroll
      for (int ni = 0; ni < 4; ni++)
        bfv[ni] = *(const short8*)(Bs[t] + (wn + ni * 16 + lrow) * 32 + quad * 8);
#pragma unroll
      for (int mi = 0; mi < 2; mi++)
#pragma unroll
        for (int ni = 0; ni < 4; ni++)
          acc[mi][ni] = __builtin_amdgcn_mfma_f32_16x16x32_bf16(af[mi], bfv[ni], acc[mi][ni], 0, 0, 0);
    }
    __syncthreads();
  }

  // fused epilogue: + bias + residual -> fp32 (16-lane x 4B = full 64B segments)
#pragma unroll
  for (int ni = 0; ni < 4; ni++) {
    int col = n0 + wn + ni * 16 + lrow;
    float bc = bias[col];
#pragma unroll
    for (int mi = 0; mi < 2; mi++) {
#pragma unroll
      for (int r = 0; r < 4; r++) {
        int row = m0 + wm + mi * 16 + quad * 4 + r;
        size_t idx = (size_t)row * N + col;
        out[idx] = acc[mi][ni][r] + bc + res[idx];
      }
    }
  }
}

// ---------------- launch --------------------------------------------------------
extern "C" void kernel_launch(void* const* d_in, const int* in_sizes, int n_in,
                              void* d_out, int out_size, void* d_ws, size_t ws_size,
                              hipStream_t stream) {
  (void)in_sizes; (void)n_in; (void)out_size; (void)ws_size;
  const float* x   = (const float*)d_in[0];
  const float* g1  = (const float*)d_in[1];
  const float* be1 = (const float*)d_in[2];
  const float* Wq  = (const float*)d_in[3];
  const float* bq  = (const float*)d_in[4];
  const float* Wk  = (const float*)d_in[5];
  const float* bk  = (const float*)d_in[6];
  const float* Wv  = (const float*)d_in[7];
  const float* bv  = (const float*)d_in[8];
  const float* g2  = (const float*)d_in[9];
  const float* be2 = (const float*)d_in[10];
  const float* W1  = (const float*)d_in[11];
  const float* bm1 = (const float*)d_in[12];
  const float* W2  = (const float*)d_in[13];
  const float* bm2 = (const float*)d_in[14];
  float* outp = (float*)d_out;

  char* ws = (char*)d_ws;
  float*    out1 = (float*)ws;                   // [0, 25165824)
  ushort_t* hb   = (ushort_t*)ws;                // bf16 h, pre-attn only
  ushort_t* qb   = (ushort_t*)(ws + 25165824);
  ushort_t* kb   = (ushort_t*)(ws + 37748736);
  ushort_t* vtb  = (ushort_t*)(ws + 50331648);   // V transposed [bh][64][256]
  ushort_t* h2   = qb;                           // reuse q after attn
  ushort_t* mb   = (ushort_t*)(ws + 37748736);   // overlays k,vt
  ushort_t* Wc   = (ushort_t*)(ws + 88080384);
  ushort_t* W1b  = (ushort_t*)(ws + 88375296);
  ushort_t* W2b  = (ushort_t*)(ws + 93093888);
  float*    bcb  = (float*)(ws + 97812480);

  k_prep<<<dim3(5184), dim3(256), 0, stream>>>(Wq, Wk, Wv, bq, bk, bv, W1, W2,
                                               Wc, bcb, W1b, W2b);
  k_ln1<<<dim3(NT), dim3(256), 0, stream>>>(x, g1, be1, hb);
  k_qkv<<<dim3(Bn * Hn * 2), dim3(256), 0, stream>>>(hb, Wc, bcb, qb, kb, vtb);
  k_attn<<<dim3(Bn * Hn * 4), dim3(256), 0, stream>>>(qb, kb, vtb, x, out1);
  k_ln2<<<dim3(NT), dim3(256), 0, stream>>>(out1, g2, be2, h2);
  k_gemm1<<<dim3(768), dim3(512), 0, stream>>>(h2, W1b, bm1, mb);
  k_gemm2<<<dim3(768), dim3(256), 0, stream>>>(mb, W2b, bm2, out1, outp);
}

// Round 14
// 293.231 us; speedup vs baseline: 1.1590x; 1.0171x over previous
//
#include <hip/hip_runtime.h>
#include <hip/hip_bf16.h>
#include <math.h>

// ViT block, B=32 S=256 D=768 H=12 HD=64 MLP=3072. fp32 I/O, bf16 MFMA inside.
//
// ws layout (total ~97.9 MB):
//   [0,        25165824)  out1 fp32 [8192][768] residual trunk; hb bf16 pre-attn
//   [25165824, 37748736)  q bf16 ; h2 bf16 after attn
//   [37748736, 50331648)  k  bf16             ; overlaid by mb after attn
//   [50331648, 62914560)  vt bf16 [B,H,64,S]  ; overlaid by mb after attn
//   [37748736, 88080384)  mb bf16 [8192][3072] gelu(fc1)
//   [88080384, 88375296)  Wc  bf16 [12][192][64] packed qkv weights
//   [88375296, 93093888)  W1b bf16 [3072][768]
//   [93093888, 97812480)  W2b bf16 [768][3072]
//   [97812480, 97821696)  bcb fp32 [12][192] packed qkv bias
//
// Journal notes baked in:
//  - SQ_LDS_BANK_CONFLICT ~4.7M is the async-DMA LDS-write burst, not frag reads.
//  - r13 WIN: XCD swizzle (xcd=b&7 owns contiguous row-tile band, columns fastest)
//    cut fc1 FETCH 58->45 MB, fc2 175->? (left top5). Keep forever.
//  - r14: fc1 was LDS-capped at 2 blk/CU (Cs 69.6KB) with a 256-block tail.
//    Two-pass Cs (34.8KB) -> LDS 48KB -> 3 blk/CU, all 768 blocks resident.

static constexpr int Bn = 32, Sn = 256, Dn = 768, Hn = 12, HDn = 64, MLPn = 3072;
static constexpr int NT = Bn * Sn; // 8192 tokens

typedef unsigned short ushort_t;
typedef unsigned int u32;
typedef __attribute__((ext_vector_type(8))) short short8; // 8 bf16 MFMA A/B frag
typedef __attribute__((ext_vector_type(4))) float f32x4;  // MFMA C/D frag

__device__ __forceinline__ float bf2f(ushort_t u) { return __uint_as_float(((u32)u) << 16); }
__device__ __forceinline__ ushort_t f2bf(float f) { // round-to-nearest-even
  u32 u = __float_as_uint(f);
  u += 0x7fffu + ((u >> 16) & 1u);
  return (ushort_t)(u >> 16);
}

// async global->LDS 16B per lane; LDS dest = wave-uniform base + lane*16 (m97/m104)
__device__ __forceinline__ void async_cp16(const ushort_t* g, ushort_t* l) {
  __builtin_amdgcn_global_load_lds(
      (const __attribute__((address_space(1))) u32*)g,
      (__attribute__((address_space(3))) u32*)l, 16, 0, 0);
}

// ------- kernel 0: weight prep + LN1 in ONE launch (independent work) ----------
// blocks [0,576)      : pack Wq|Wk|Wv -> Wc bf16 + bias -> bcb
// blocks [576,5184)   : W1/W2 -> bf16
// blocks [5184,13376) : LN1 (one block per token) -> hb bf16
__global__ __launch_bounds__(256) void k_prep(
    const float* __restrict__ Wq, const float* __restrict__ Wk,
    const float* __restrict__ Wv, const float* __restrict__ bq,
    const float* __restrict__ bk, const float* __restrict__ bv,
    const float* __restrict__ W1, const float* __restrict__ W2,
    const float* __restrict__ x, const float* __restrict__ g1,
    const float* __restrict__ be1,
    ushort_t* __restrict__ Wc, float* __restrict__ bc,
    ushort_t* __restrict__ W1b, ushort_t* __restrict__ W2b,
    ushort_t* __restrict__ hb)
{
  __shared__ float red[8];
  const int bx = blockIdx.x;
  const int tid = threadIdx.x;
  if (bx < 576) {
    int i = bx * 256 + tid; // 0 .. 147455
    int h = i / 12288, rem = i - h * 12288;
    int mat = rem / 4096, w = rem - mat * 4096;
    const float* src = (mat == 0) ? Wq : ((mat == 1) ? Wk : Wv);
    Wc[i] = f2bf(src[h * 4096 + w]);
    if (i < Hn * 192) {
      int h2 = i / 192, r2 = i - h2 * 192;
      int m2 = r2 / 64, e2 = r2 - m2 * 64;
      const float* bs = (m2 == 0) ? bq : ((m2 == 1) ? bk : bv);
      bc[i] = bs[h2 * 64 + e2];
    }
  } else if (bx < 5184) {
    int j = bx - 576;
    const float* src = (j < 2304) ? W1 : W2;
    ushort_t* dst = (j < 2304) ? W1b : W2b;
    int i = (j % 2304) * 256 + tid; // float4 index < 589824
    float4 v = ((const float4*)src)[i];
    ushort4 o;
    o.x = f2bf(v.x); o.y = f2bf(v.y); o.z = f2bf(v.z); o.w = f2bf(v.w);
    ((ushort4*)dst)[i] = o;
  } else {
    const int t = bx - 5184;
    float xv[3];
#pragma unroll
    for (int i = 0; i < 3; i++) xv[i] = x[(size_t)t * Dn + tid + i * 256];
    float s = xv[0] + xv[1] + xv[2];
#pragma unroll
    for (int off = 32; off > 0; off >>= 1) s += __shfl_down(s, off, 64);
    if ((tid & 63) == 0) red[tid >> 6] = s;
    __syncthreads();
    float mean = (red[0] + red[1] + red[2] + red[3]) * (1.0f / 768.0f);
    float d0 = xv[0] - mean, d1 = xv[1] - mean, d2 = xv[2] - mean;
    float s2 = d0 * d0 + d1 * d1 + d2 * d2;
#pragma unroll
    for (int off = 32; off > 0; off >>= 1) s2 += __shfl_down(s2, off, 64);
    if ((tid & 63) == 0) red[4 + (tid >> 6)] = s2;
    __syncthreads();
    float rstd = rsqrtf((red[4] + red[5] + red[6] + red[7]) * (1.0f / 768.0f) + 1e-5f);
#pragma unroll
    for (int i = 0; i < 3; i++) {
      int d = tid + i * 256;
      hb[(size_t)t * Dn + d] = f2bf((xv[i] - mean) * rstd * g1[d] + be1[d]);
    }
  }
}

// ---------------- kernel 2: QKV projection via MFMA ----------------------------
__global__ __launch_bounds__(256) void k_qkv(
    const ushort_t* __restrict__ hb,  // [NT][768] bf16
    const ushort_t* __restrict__ Wc,  // [12][192][64] bf16
    const float* __restrict__ bc,     // [12][192] fp32
    ushort_t* __restrict__ qo, ushort_t* __restrict__ ko, ushort_t* __restrict__ vt)
{
  __shared__ __align__(16) ushort_t As[128 * 72];
  __shared__ __align__(16) ushort_t Ws[192 * 72];
  const int blk = blockIdx.x;         // (b*12 + h)*2 + half
  const int half = blk & 1;
  const int bh = blk >> 1;
  const int b_ = bh / Hn, h_ = bh - b_ * Hn;
  const int tid = threadIdx.x;
  const int t0 = b_ * Sn + half * 128;

  { // stage A: 128 rows x 64 cols (head slice of hb)
    int row = tid >> 1, seg = (tid & 1) * 32;
    const uint4* g = (const uint4*)(hb + (size_t)(t0 + row) * Dn + h_ * 64 + seg);
    uint4* s = (uint4*)(As + row * 72 + seg);
    s[0] = g[0]; s[1] = g[1]; s[2] = g[2]; s[3] = g[3];
  }
  { // stage W: 192 rows x 64 cols, contiguous per head
    int rr = tid >> 2, seg = (tid & 3) * 16;
    const ushort_t* gw = Wc + h_ * 12288;
#pragma unroll
    for (int p = 0; p < 3; p++) {
      int R = p * 64 + rr;
      const uint4* g = (const uint4*)(gw + R * 64 + seg);
      uint4* s = (uint4*)(Ws + R * 72 + seg);
      s[0] = g[0]; s[1] = g[1];
    }
  }
  __syncthreads();

  const int wave = tid >> 6, lane = tid & 63;
  const int wm = (wave >> 1) * 64, wn = (wave & 1) * 96;
  const int lrow = lane & 15, quad = lane >> 4;

  f32x4 acc[4][6];
#pragma unroll
  for (int mi = 0; mi < 4; mi++)
#pragma unroll
    for (int ni = 0; ni < 6; ni++) acc[mi][ni] = (f32x4){0.f, 0.f, 0.f, 0.f};

#pragma unroll
  for (int kk = 0; kk < 2; kk++) {
    short8 af[4], wf[6];
#pragma unroll
    for (int mi = 0; mi < 4; mi++)
      af[mi] = *(const short8*)(As + (wm + mi * 16 + lrow) * 72 + kk * 32 + quad * 8);
#pragma unroll
    for (int ni = 0; ni < 6; ni++)
      wf[ni] = *(const short8*)(Ws + (wn + ni * 16 + lrow) * 72 + kk * 32 + quad * 8);
#pragma unroll
    for (int mi = 0; mi < 4; mi++)
#pragma unroll
      for (int ni = 0; ni < 6; ni++)
        acc[mi][ni] = __builtin_amdgcn_mfma_f32_16x16x32_bf16(af[mi], wf[ni], acc[mi][ni], 0, 0, 0);
  }

#pragma unroll
  for (int ni = 0; ni < 6; ni++) {
    int c = wn + ni * 16 + lrow;        // 0..191, mat uniform per (wave,ni)
    int mat = c >> 6, e = c & 63;
    float bb = bc[h_ * 192 + c];
    if (mat < 2) {
      ushort_t* dst = (mat == 0) ? qo : ko;
      size_t base = (((size_t)bh) * Sn + half * 128 + wm) * HDn + e;
#pragma unroll
      for (int mi = 0; mi < 4; mi++) {
#pragma unroll
        for (int r = 0; r < 4; r++) {
          int lr = mi * 16 + quad * 4 + r;
          dst[base + (size_t)lr * HDn] = f2bf(acc[mi][ni][r] + bb);
        }
      }
    } else {
      size_t rowb = ((size_t)bh * 64 + e) * Sn + half * 128 + wm + quad * 4;
#pragma unroll
      for (int mi = 0; mi < 4; mi++) {
        ushort4 pk;
        pk.x = f2bf(acc[mi][ni][0] + bb);
        pk.y = f2bf(acc[mi][ni][1] + bb);
        pk.z = f2bf(acc[mi][ni][2] + bb);
        pk.w = f2bf(acc[mi][ni][3] + bb);
        *(ushort4*)(vt + rowb + mi * 16) = pk;
      }
    }
  }
}

// ---------------- kernel 3: MFMA flash attention -------------------------------
__global__ __launch_bounds__(256) void k_attn(
    const ushort_t* __restrict__ q,   // [bh][s][64]
    const ushort_t* __restrict__ kg_, // [bh][s][64]
    const ushort_t* __restrict__ vt,  // [bh][e=64][s=256]
    const float* __restrict__ x,
    float* __restrict__ out1)
{
  __shared__ __align__(16) ushort_t Ks[64 * 72];
  __shared__ __align__(16) ushort_t Vts[64 * 264];
  __shared__ __align__(16) ushort_t Pw[4][16 * 72];
  const int blk = blockIdx.x;          // bh*4 + quarter
  const int qtr = blk & 3, bh = blk >> 2;
  const int b_ = bh / Hn, h_ = bh - b_ * Hn;
  const int tid = threadIdx.x, wave = tid >> 6, lane = tid & 63;
  const int lr16 = lane & 15, quad = lane >> 4;
  const int s0 = qtr * 64 + wave * 16;

  { // stage Vt whole head
    int r = tid >> 2, cseg = (tid & 3) * 64;
    const uint4* g = (const uint4*)(vt + ((size_t)bh * 64 + r) * Sn + cseg);
    uint4* s = (uint4*)(Vts + r * 264 + cseg);
#pragma unroll
    for (int i = 0; i < 8; i++) s[i] = g[i];
  }

  short8 qf[2];
  {
    const ushort_t* qg = q + ((size_t)bh * Sn + s0 + lr16) * HDn + quad * 8;
    qf[0] = *(const short8*)(qg);
    qf[1] = *(const short8*)(qg + 32);
  }

  f32x4 of[4];
#pragma unroll
  for (int et = 0; et < 4; et++) of[et] = (f32x4){0.f, 0.f, 0.f, 0.f};
  float mrow[4] = {-3.0e38f, -3.0e38f, -3.0e38f, -3.0e38f};
  float lsum[4] = {0.f, 0.f, 0.f, 0.f};

  const ushort_t* kgb = kg_ + (size_t)bh * Sn * HDn;

  for (int c = 0; c < 4; c++) {
    if (c) __syncthreads();
    {
      int row = tid >> 2, seg = (tid & 3) * 16;
      const uint4* g = (const uint4*)(kgb + (size_t)(c * 64 + row) * HDn + seg);
      uint4* s = (uint4*)(Ks + row * 72 + seg);
      s[0] = g[0]; s[1] = g[1];
    }
    __syncthreads();

    f32x4 sc[4];
#pragma unroll
    for (int ni = 0; ni < 4; ni++) sc[ni] = (f32x4){0.f, 0.f, 0.f, 0.f};
#pragma unroll
    for (int kk = 0; kk < 2; kk++) {
#pragma unroll
      for (int ni = 0; ni < 4; ni++) {
        short8 kf = *(const short8*)(Ks + (ni * 16 + lr16) * 72 + kk * 32 + quad * 8);
        sc[ni] = __builtin_amdgcn_mfma_f32_16x16x32_bf16(qf[kk], kf, sc[ni], 0, 0, 0);
      }
    }

    float alpha[4];
#pragma unroll
    for (int r = 0; r < 4; r++) {
      float m_ = fmaxf(fmaxf(sc[0][r], sc[1][r]), fmaxf(sc[2][r], sc[3][r]));
#pragma unroll
      for (int msk = 8; msk >= 1; msk >>= 1) m_ = fmaxf(m_, __shfl_xor(m_, msk, 64));
      float mn = fmaxf(mrow[r], m_);
      alpha[r] = __expf((mrow[r] - mn) * 0.125f);
      mrow[r] = mn;
    }
#pragma unroll
    for (int ni = 0; ni < 4; ni++) {
#pragma unroll
      for (int r = 0; r < 4; r++) {
        float p = __expf((sc[ni][r] - mrow[r]) * 0.125f);
        sc[ni][r] = p;
        Pw[wave][(quad * 4 + r) * 72 + ni * 16 + lr16] = f2bf(p);
      }
    }
#pragma unroll
    for (int r = 0; r < 4; r++) {
      float s_ = (sc[0][r] + sc[1][r]) + (sc[2][r] + sc[3][r]);
#pragma unroll
      for (int msk = 8; msk >= 1; msk >>= 1) s_ += __shfl_xor(s_, msk, 64);
      lsum[r] = lsum[r] * alpha[r] + s_;
    }
#pragma unroll
    for (int et = 0; et < 4; et++)
#pragma unroll
      for (int r = 0; r < 4; r++) of[et][r] *= alpha[r];

    short8 pf0 = *(const short8*)(&Pw[wave][lr16 * 72 + quad * 8]);
    short8 pf1 = *(const short8*)(&Pw[wave][lr16 * 72 + 32 + quad * 8]);
#pragma unroll
    for (int et = 0; et < 4; et++) {
      short8 vf0 = *(const short8*)(Vts + (et * 16 + lr16) * 264 + c * 64 + quad * 8);
      short8 vf1 = *(const short8*)(Vts + (et * 16 + lr16) * 264 + c * 64 + 32 + quad * 8);
      of[et] = __builtin_amdgcn_mfma_f32_16x16x32_bf16(pf0, vf0, of[et], 0, 0, 0);
      of[et] = __builtin_amdgcn_mfma_f32_16x16x32_bf16(pf1, vf1, of[et], 0, 0, 0);
    }
  }

  const size_t obase = ((size_t)b_ * Sn + s0) * Dn + h_ * 64;
#pragma unroll
  for (int r = 0; r < 4; r++) {
    float rl = 1.0f / lsum[r];
    int row = quad * 4 + r;
#pragma unroll
    for (int et = 0; et < 4; et++) {
      size_t idx = obase + (size_t)row * Dn + et * 16 + lr16;
      out1[idx] = of[et][r] * rl + x[idx];
    }
  }
}

// ---------------- kernel 4: LN2 (one WG per token) -----------------------------
__global__ __launch_bounds__(256) void k_ln2(
    const float* __restrict__ in, const float* __restrict__ g2,
    const float* __restrict__ be2, ushort_t* __restrict__ h2)
{
  const int t = blockIdx.x, tid = threadIdx.x;
  __shared__ float red[8];
  float xv[3];
#pragma unroll
  for (int i = 0; i < 3; i++) xv[i] = in[(size_t)t * Dn + tid + i * 256];
  float s = xv[0] + xv[1] + xv[2];
#pragma unroll
  for (int off = 32; off > 0; off >>= 1) s += __shfl_down(s, off, 64);
  if ((tid & 63) == 0) red[tid >> 6] = s;
  __syncthreads();
  float mean = (red[0] + red[1] + red[2] + red[3]) * (1.0f / 768.0f);
  float d0 = xv[0] - mean, d1 = xv[1] - mean, d2 = xv[2] - mean;
  float s2 = d0 * d0 + d1 * d1 + d2 * d2;
#pragma unroll
  for (int off = 32; off > 0; off >>= 1) s2 += __shfl_down(s2, off, 64);
  if ((tid & 63) == 0) red[4 + (tid >> 6)] = s2;
  __syncthreads();
  float rstd = rsqrtf((red[4] + red[5] + red[6] + red[7]) * (1.0f / 768.0f) + 1e-5f);
#pragma unroll
  for (int i = 0; i < 3; i++) {
    int d = tid + i * 256;
    h2[(size_t)t * Dn + d] = f2bf((xv[i] - mean) * rstd * g2[d] + be2[d]);
  }
}

// ---- kernel 5: fc1 MFMA GEMM, 512 threads, 256x128 tile, XCD-swizzled grid ----
// LDS = 48KB staging only (Cs 128x136 two-pass unioned inside) -> 3 blocks/CU,
// all 768 blocks resident (no tail).
__global__ __launch_bounds__(512) void k_gemm1(
    const ushort_t* __restrict__ A,   // h2 [8192][768] bf16
    const ushort_t* __restrict__ Bw,  // W1b [3072][768] bf16
    const float* __restrict__ bias,   // bm1 [3072]
    ushort_t* __restrict__ CoutB)     // mb [8192][3072] bf16
{
  constexpr int KDIM = Dn, N = MLPn;
  __shared__ __align__(16) ushort_t smem[24576];      // 48KB staging / Cs 128x136
  ushort_t* Asb[2] = { smem, smem + 12288 };          // each 256*32 = 8192
  ushort_t* Bsb[2] = { smem + 8192, smem + 20480 };   // each 128*32 = 4096
  ushort_t* Cs = smem;                                 // 17408 ushorts (34.8KB)
  const int b = blockIdx.x;
  const int xcd = b & 7, slot = b >> 3;   // 96 slots per XCD
  const int cc = slot % 24, rloc = slot / 24;
  const int m0 = (xcd * 4 + rloc) * 256, n0 = cc * 128;
  const int tid = threadIdx.x;
  const int wave = tid >> 6, lane = tid & 63;         // wave 0..7
  const int wm = (wave >> 1) << 6, wn = (wave & 1) << 6;
  const int lrow = lane & 15, quad = lane >> 4;
  const int lrow4 = lane >> 2, lcol8 = (lane & 3) * 8;

  f32x4 acc[4][4];
#pragma unroll
  for (int mi = 0; mi < 4; mi++)
#pragma unroll
    for (int ni = 0; ni < 4; ni++) acc[mi][ni] = (f32x4){0.f, 0.f, 0.f, 0.f};

  for (int k0 = 0; k0 < KDIM; k0 += 64) {
#pragma unroll
    for (int t = 0; t < 2; t++) {
      async_cp16(A + (size_t)(m0 + wave * 16 + lrow4) * KDIM + k0 + t * 32 + lcol8,
                 Asb[t] + (wave * 16) * 32);
      async_cp16(A + (size_t)(m0 + 128 + wave * 16 + lrow4) * KDIM + k0 + t * 32 + lcol8,
                 Asb[t] + (128 + wave * 16) * 32);
      async_cp16(Bw + (size_t)(n0 + wave * 16 + lrow4) * KDIM + k0 + t * 32 + lcol8,
                 Bsb[t] + (wave * 16) * 32);
    }
    __syncthreads();
#pragma unroll
    for (int t = 0; t < 2; t++) {
      short8 af[4], bfv[4];
#pragma unroll
      for (int mi = 0; mi < 4; mi++)
        af[mi] = *(const short8*)(Asb[t] + (wm + mi * 16 + lrow) * 32 + quad * 8);
#pragma unroll
      for (int ni = 0; ni < 4; ni++)
        bfv[ni] = *(const short8*)(Bsb[t] + (wn + ni * 16 + lrow) * 32 + quad * 8);
#pragma unroll
      for (int mi = 0; mi < 4; mi++)
#pragma unroll
        for (int ni = 0; ni < 4; ni++)
          acc[mi][ni] = __builtin_amdgcn_mfma_f32_16x16x32_bf16(af[mi], bfv[ni], acc[mi][ni], 0, 0, 0);
    }
    __syncthreads();
  }

  // tanh-exp GELU + two-pass LDS-coalesced bf16 epilogue (Cs = 128 rows x 136)
#pragma unroll
  for (int p = 0; p < 2; p++) {
    if ((wm >> 7) == p) {            // waves owning rows [p*128, p*128+128)
#pragma unroll
      for (int ni = 0; ni < 4; ni++) {
        int col = wn + ni * 16 + lrow;
        float bc = bias[n0 + col];
#pragma unroll
        for (int mi = 0; mi < 4; mi++) {
#pragma unroll
          for (int r = 0; r < 4; r++) {
            float vv = acc[mi][ni][r] + bc;
            float u = vv * (0.7978845608f + 0.0356774081f * vv * vv);
            float o = vv / (1.0f + __expf(-2.0f * u));
            Cs[((wm & 127) + mi * 16 + quad * 4 + r) * 136 + col] = f2bf(o);
          }
        }
      }
    }
    __syncthreads();
    int row = tid >> 2, part = tid & 3;   // 512 thr -> 128 rows x 4 chunks of 64B
    const uint4* s = (const uint4*)(Cs + row * 136 + part * 32);
    uint4* d = (uint4*)(CoutB + (size_t)(m0 + p * 128 + row) * N + n0 + part * 32);
#pragma unroll
    for (int i = 0; i < 4; i++) d[i] = s[i];
    if (p == 0) __syncthreads();
  }
}

// ---- kernel 6: fc2 MFMA GEMM, 64x128 tile, full K, XCD-swizzled grid ----------
__global__ __launch_bounds__(256) void k_gemm2(
    const ushort_t* __restrict__ A,   // mb [8192][3072] bf16
    const ushort_t* __restrict__ Bw,  // W2b [768][3072] bf16
    const float* __restrict__ bias,   // bm2 [768]
    const float* __restrict__ res,    // out1 [8192][768] fp32
    float* __restrict__ out)          // d_out [8192][768] fp32
{
  constexpr int KDIM = MLPn, N = Dn;
  __shared__ __align__(16) ushort_t As[2][64 * 32];   // 8 KB
  __shared__ __align__(16) ushort_t Bs[2][128 * 32];  // 16 KB
  const int b = blockIdx.x;
  const int xcd = b & 7, slot = b >> 3;   // 96 slots per XCD
  const int cc = slot % 6, rloc = slot / 6;
  const int m0 = (xcd * 16 + rloc) * 64, n0 = cc * 128;
  const int tid = threadIdx.x;
  const int wave = tid >> 6, lane = tid & 63;
  const int wm = (wave >> 1) << 5, wn = (wave & 1) << 6; // 32-row, 64-col wave tile
  const int lrow = lane & 15, quad = lane >> 4;
  const int lrow4 = lane >> 2, lcol8 = (lane & 3) * 8;

  f32x4 acc[2][4];
#pragma unroll
  for (int mi = 0; mi < 2; mi++)
#pragma unroll
    for (int ni = 0; ni < 4; ni++) acc[mi][ni] = (f32x4){0.f, 0.f, 0.f, 0.f};

  for (int k0 = 0; k0 < KDIM; k0 += 64) {
#pragma unroll
    for (int t = 0; t < 2; t++) {
      int rr = wave * 16;
      async_cp16(A + (size_t)(m0 + rr + lrow4) * KDIM + k0 + t * 32 + lcol8, As[t] + rr * 32);
#pragma unroll
      for (int a = 0; a < 2; a++) {
        int rb = rr + a * 64;
        async_cp16(Bw + (size_t)(n0 + rb + lrow4) * KDIM + k0 + t * 32 + lcol8, Bs[t] + rb * 32);
      }
    }
    __syncthreads();
#pragma unroll
    for (int t = 0; t < 2; t++) {
      short8 af[2], bfv[4];
#pragma unroll
      for (int mi = 0; mi < 2; mi++)
        af[mi] = *(const short8*)(As[t] + (wm + mi * 16 + lrow) * 32 + quad * 8);
#pragma unroll
      for (int ni = 0; ni < 4; ni++)
        bfv[ni] = *(const short8*)(Bs[t] + (wn + ni * 16 + lrow) * 32 + quad * 8);
#pragma unroll
      for (int mi = 0; mi < 2; mi++)
#pragma unroll
        for (int ni = 0; ni < 4; ni++)
          acc[mi][ni] = __builtin_amdgcn_mfma_f32_16x16x32_bf16(af[mi], bfv[ni], acc[mi][ni], 0, 0, 0);
    }
    __syncthreads();
  }

  // fused epilogue: + bias + residual -> fp32 (16-lane x 4B = full 64B segments)
#pragma unroll
  for (int ni = 0; ni < 4; ni++) {
    int col = n0 + wn + ni * 16 + lrow;
    float bc = bias[col];
#pragma unroll
    for (int mi = 0; mi < 2; mi++) {
#pragma unroll
      for (int r = 0; r < 4; r++) {
        int row = m0 + wm + mi * 16 + quad * 4 + r;
        size_t idx = (size_t)row * N + col;
        out[idx] = acc[mi][ni][r] + bc + res[idx];
      }
    }
  }
}

// ---------------- launch --------------------------------------------------------
extern "C" void kernel_launch(void* const* d_in, const int* in_sizes, int n_in,
                              void* d_out, int out_size, void* d_ws, size_t ws_size,
                              hipStream_t stream) {
  (void)in_sizes; (void)n_in; (void)out_size; (void)ws_size;
  const float* x   = (const float*)d_in[0];
  const float* g1  = (const float*)d_in[1];
  const float* be1 = (const float*)d_in[2];
  const float* Wq  = (const float*)d_in[3];
  const float* bq  = (const float*)d_in[4];
  const float* Wk  = (const float*)d_in[5];
  const float* bk  = (const float*)d_in[6];
  const float* Wv  = (const float*)d_in[7];
  const float* bv  = (const float*)d_in[8];
  const float* g2  = (const float*)d_in[9];
  const float* be2 = (const float*)d_in[10];
  const float* W1  = (const float*)d_in[11];
  const float* bm1 = (const float*)d_in[12];
  const float* W2  = (const float*)d_in[13];
  const float* bm2 = (const float*)d_in[14];
  float* outp = (float*)d_out;

  char* ws = (char*)d_ws;
  float*    out1 = (float*)ws;                   // [0, 25165824)
  ushort_t* hb   = (ushort_t*)ws;                // bf16 h, pre-attn only
  ushort_t* qb   = (ushort_t*)(ws + 25165824);
  ushort_t* kb   = (ushort_t*)(ws + 37748736);
  ushort_t* vtb  = (ushort_t*)(ws + 50331648);   // V transposed [bh][64][256]
  ushort_t* h2   = qb;                           // reuse q after attn
  ushort_t* mb   = (ushort_t*)(ws + 37748736);   // overlays k,vt
  ushort_t* Wc   = (ushort_t*)(ws + 88080384);
  ushort_t* W1b  = (ushort_t*)(ws + 88375296);
  ushort_t* W2b  = (ushort_t*)(ws + 93093888);
  float*    bcb  = (float*)(ws + 97812480);

  k_prep<<<dim3(5184 + NT), dim3(256), 0, stream>>>(Wq, Wk, Wv, bq, bk, bv, W1, W2,
                                                    x, g1, be1, Wc, bcb, W1b, W2b, hb);
  k_qkv<<<dim3(Bn * Hn * 2), dim3(256), 0, stream>>>(hb, Wc, bcb, qb, kb, vtb);
  k_attn<<<dim3(Bn * Hn * 4), dim3(256), 0, stream>>>(qb, kb, vtb, x, out1);
  k_ln2<<<dim3(NT), dim3(256), 0, stream>>>(out1, g2, be2, h2);
  k_gemm1<<<dim3(768), dim3(512), 0, stream>>>(h2, W1b, bm1, mb);
  k_gemm2<<<dim3(768), dim3(256), 0, stream>>>(mb, W2b, bm2, out1, outp);
}